// Round 4
// baseline (683.263 us; speedup 1.0000x reference)
//
#include <hip/hip_runtime.h>
#include <hip/hip_bf16.h>
#include <math.h>

// GAT: N=100000 nodes, E=1600000 edges (+N self loops), 3 layers.
// Inputs bf16 (runtime-detected flag kept). Intermediates bf16.
// CSR build: atomic-free counting sort (8 dst-range buckets, round-2 form).
// Aggregation: h stored as 16-channel PLANES [cb][node][16ch] (32B rows,
// 3.2MB per plane -> L2-resident per XCD). Each block owns 128 dsts
// (2 lanes/dst) and loops cb=0..NCB-1 internally so all resident blocks
// walk one plane at a time. Final layer: head-paired planes -> head mean
// via shfl_xor, no staging buffer.

#define NNODES 100000
#define NND    100032              // padded node count (plane row stride)
#define NEDGES 1600000
#define ENTOT  (NEDGES + NNODES)
#define NEG_SLOPE 0.2f
#define BN_EPS 1e-5f

#define NRANGE 8
#define RSIZE  (NNODES/NRANGE)     // 12500
#define BCAP   262144              // per-bucket capacity (mean 212.5k)
#define PBLK   2048                // partition blocks
#define NB2    32                  // chunks per range

typedef unsigned short u16;
typedef unsigned int u32;
typedef unsigned long long u64;
typedef __attribute__((ext_vector_type(8))) short short8;
typedef __attribute__((ext_vector_type(4))) float f32x4;

__device__ __forceinline__ float b2f(u16 u){ union{u32 i; float f;} v; v.i=((u32)u)<<16; return v.f; }
__device__ __forceinline__ float blo(u32 u){ union{u32 i; float f;} v; v.i=u<<16; return v.f; }
__device__ __forceinline__ float bhi(u32 u){ union{u32 i; float f;} v; v.i=u&0xffff0000u; return v.f; }
__device__ __forceinline__ u16 f2b(float x){ __hip_bfloat16 b=__float2bfloat16(x); return *(u16*)&b; }
__device__ __forceinline__ float ldf(const void* p, int i, int f){
  return f ? ((const float*)p)[i] : b2f(((const u16*)p)[i]);
}

// ---------------- dtype probe ----------------
__global__ void k_detect(const u16* __restrict__ x, int* __restrict__ flag){
  __shared__ int bad;
  if(threadIdx.x==0) bad=0;
  __syncthreads();
  int cnt=0;
  for(int i=threadIdx.x;i<4096;i+=256){
    u16 v = x[2*i];
    int ex = (v>>7)&0xff;
    if(ex==0xff || (ex==0 && (v&0x7fff)!=0)) cnt++;
  }
  atomicAdd(&bad,cnt);
  __syncthreads();
  if(threadIdx.x==0) flag[0] = (bad>4)?1:0;   // 1 = fp32, 0 = bf16
}

// ---------------- pass A: partition edges into 8 dst-range buckets ---------
__global__ __launch_bounds__(256) void k_part2(
    const int* __restrict__ ei, int* __restrict__ gptr, u32* __restrict__ bkt){
  __shared__ int lcnt[NRANGE], gbase[NRANGE];
  int t=threadIdx.x;
  if(t<NRANGE) lcnt[t]=0;
  __syncthreads();
  const int CH=(ENTOT+PBLK-1)/PBLK;   // 831
  int beg=blockIdx.x*CH, end=beg+CH; if(end>ENTOT) end=ENTOT;
  int nd[4], ns[4], nr[4], ne=0;
  for(int i=beg+t; i<end; i+=256){
    int d=(i<NEDGES)? ei[NEDGES+i] : (i-NEDGES);
    int s=(i<NEDGES)? ei[i] : d;
    nd[ne]=d; ns[ne]=s; ne++;
  }
  #pragma unroll 4
  for(int k=0;k<ne;k++) nr[k]=atomicAdd(&lcnt[nd[k]/RSIZE],1);
  __syncthreads();
  if(t<NRANGE) gbase[t]=atomicAdd(&gptr[t],lcnt[t]);
  __syncthreads();
  #pragma unroll 4
  for(int k=0;k<ne;k++){
    int r=nd[k]/RSIZE;
    u32 e = ((u32)(nd[k]-r*RSIZE)<<17) | (u32)ns[k];   // dst_local(14b)|src(17b)
    __builtin_nontemporal_store(e, &bkt[(size_t)r*BCAP + gbase[r] + nr[k]]);
  }
}

// ---------------- pass B0: per-(range,chunk) LDS histogram -----------------
__global__ __launch_bounds__(256) void k_hist4(
    const u32* __restrict__ bkt, const int* __restrict__ gptr, int* __restrict__ lhist){
  __shared__ int lh[RSIZE];
  int t=threadIdx.x;
  for(int i=t;i<RSIZE;i+=256) lh[i]=0;
  __syncthreads();
  int r = blockIdx.x & (NRANGE-1);
  int c = blockIdx.x >> 3;
  int n = gptr[r];
  int per=(n+NB2-1)/NB2;
  int beg=c*per, end=beg+per; if(end>n) end=n;
  const u32* bp = bkt + (size_t)r*BCAP;
  for(int i=beg+t;i<end;i+=256) atomicAdd(&lh[bp[i]>>17],1);
  __syncthreads();
  int* out = lhist + (size_t)(r*NB2+c)*RSIZE;
  for(int i=t;i<RSIZE;i+=256) out[i]=lh[i];
}

// ---------------- node-wise chunk-scan: cnt + in-place exclusive scan ------
__global__ __launch_bounds__(256) void k_sumscan(int* __restrict__ lhist, int* __restrict__ cnt){
  int n = blockIdx.x*256 + threadIdx.x;
  if(n>=NNODES) return;
  int r = n/RSIZE, i = n - r*RSIZE;
  int* base = lhist + (size_t)r*NB2*RSIZE + i;
  int run=0;
  #pragma unroll 8
  for(int c=0;c<NB2;c++){
    int v = base[(size_t)c*RSIZE];
    base[(size_t)c*RSIZE] = run;
    run += v;
  }
  cnt[n]=run;
}

// ---------------- prefix scan (row_ptr) ----------------
#define SCAN_M (NNODES+1)
#define SCAN_NB ((SCAN_M + 2047)/2048)

__global__ void k_scan_a(const int* __restrict__ cnt, int* __restrict__ bsum){
  __shared__ int red[256];
  int b=blockIdx.x, t=threadIdx.x;
  int base = b*2048 + t*8;
  int s=0;
  #pragma unroll
  for(int j=0;j<8;j++){ int idx=base+j; s += (idx<NNODES)? cnt[idx]:0; }
  red[t]=s; __syncthreads();
  for(int o=128;o>0;o>>=1){ if(t<o) red[t]+=red[t+o]; __syncthreads(); }
  if(t==0) bsum[b]=red[0];
}

__global__ void k_scan_b(int* bsum){
  if(threadIdx.x==0){
    int run=0;
    for(int i=0;i<SCAN_NB;i++){ int v=bsum[i]; bsum[i]=run; run+=v; }
  }
}

__global__ void k_scan_c(const int* __restrict__ cnt, const int* __restrict__ bsum,
                         int* __restrict__ row_ptr){
  __shared__ int lds[256];
  int b=blockIdx.x, t=threadIdx.x;
  int base=b*2048+t*8;
  int v[8]; int s=0;
  #pragma unroll
  for(int j=0;j<8;j++){ int idx=base+j; int x=(idx<NNODES)?cnt[idx]:0; v[j]=s; s+=x; }
  lds[t]=s; __syncthreads();
  for(int o=1;o<256;o<<=1){
    int other=0; if(t>=o) other=lds[t-o];
    __syncthreads();
    lds[t]+=other;
    __syncthreads();
  }
  int texcl = lds[t] - s;
  int off0 = bsum[b] + texcl;
  #pragma unroll
  for(int j=0;j<8;j++){ int idx=base+j; if(idx<SCAN_M) row_ptr[idx]=off0+v[j]; }
}

// ---------------- pass B1: LDS-offset scatter (no global atomics) ----------
__global__ __launch_bounds__(256) void k_scatter4(
    const u32* __restrict__ bkt, const int* __restrict__ gptr,
    const int* __restrict__ row_ptr, const int* __restrict__ lhist,
    int* __restrict__ col){
  __shared__ int lofs[RSIZE];
  int t=threadIdx.x;
  int r = blockIdx.x & (NRANGE-1);
  int c = blockIdx.x >> 3;
  int lo = r*RSIZE;
  const int* cb = lhist + (size_t)(r*NB2+c)*RSIZE;
  for(int i=t;i<RSIZE;i+=256) lofs[i] = row_ptr[lo+i] + cb[i];
  __syncthreads();
  int n = gptr[r];
  int per=(n+NB2-1)/NB2;
  int beg=c*per, end=beg+per; if(end>n) end=n;
  const u32* bp = bkt + (size_t)r*BCAP;
  for(int i=beg+t;i<end;i+=256){
    u32 e=bp[i];
    int pos=atomicAdd(&lofs[e>>17],1);
    col[pos]=(int)(e & 0x1FFFF);
  }
}

// ---------------- MFMA GEMM + fused BN/ELU + alpha epilogue ----------------
// hout is written in PLANE layout: plane p holds 16 channels per node
// (32B rows, stride NND). OUTC==64: plane p = ch [p*16, p*16+16).
// OUTC==80: head-paired: plane p = ch [p*8,p*8+8) U [40+p*8, 40+p*8+8).
template<int K, int OUTC, int HID, bool XEXT, bool BN>
__global__ __launch_bounds__(256) void k_gemm_mfma(
    const void* __restrict__ xin, const void* __restrict__ W,
    const void* __restrict__ avs, const void* __restrict__ avd,
    const float2* __restrict__ bnab,
    u16* __restrict__ hout, float* __restrict__ asrc, float* __restrict__ adst,
    const int* __restrict__ flagp)
{
  const int f = flagp[0];
  constexpr int KP = K+8;          // WT row stride (u16), 16B-aligned rows
  constexpr int RS = OUTC+8;       // HROW row stride (u16)
  constexpr int NT = OUTC/16;      // col tiles per wave
  constexpr int KQ = K/32;         // mfma K steps
  __shared__ __align__(16) u16 WT[OUTC*KP];
  __shared__ __align__(16) u16 HROW[4*16*RS];
  __shared__ float AVb[2*OUTC];
  __shared__ float2 BB[K];
  int t=threadIdx.x;
  const u16* Wu=(const u16*)W; const float* Wf=(const float*)W;
  for(int i8=t*8; i8<K*OUTC; i8+=256*8){
    int k=i8/OUTC, c0=i8-k*OUTC;     // OUTC divisible by 8 -> row-local
    u16 w8[8];
    if(f){
      const float* wp=Wf+i8;
      float4 a=*(const float4*)wp, b=*(const float4*)(wp+4);
      w8[0]=f2b(a.x);w8[1]=f2b(a.y);w8[2]=f2b(a.z);w8[3]=f2b(a.w);
      w8[4]=f2b(b.x);w8[5]=f2b(b.y);w8[6]=f2b(b.z);w8[7]=f2b(b.w);
    } else {
      uint4 q=*(const uint4*)(Wu+i8);
      w8[0]=q.x&0xffff;w8[1]=q.x>>16;w8[2]=q.y&0xffff;w8[3]=q.y>>16;
      w8[4]=q.z&0xffff;w8[5]=q.z>>16;w8[6]=q.w&0xffff;w8[7]=q.w>>16;
    }
    #pragma unroll
    for(int u=0;u<8;u++) WT[(c0+u)*KP + k] = w8[u];
  }
  for(int idx=t; idx<2*OUTC; idx+=256)
    AVb[idx] = (idx<OUTC)? ldf(avs,idx,f) : ldf(avd,idx-OUTC,f);
  if(BN) for(int idx=t; idx<K; idx+=256) BB[idx]=bnab[idx];
  __syncthreads();

  int wv=t>>6, lane=t&63;
  int m=lane&15, quad=lane>>4;
  int grow0 = blockIdx.x*64 + wv*16;
  int growA = grow0 + m;
  bool avalid = growA < NNODES;
  int growC = avalid ? growA : 0;

  f32x4 acc[NT] = {};
  #pragma unroll
  for(int kq=0;kq<KQ;kq++){
    int k0 = kq*32 + quad*8;
    union{ u32 u[4]; short8 s8; } A;
    if(XEXT && f==1){
      const float* xr=(const float*)xin + (size_t)growC*K + k0;
      float4 p=*(const float4*)xr, q=*(const float4*)(xr+4);
      A.u[0]=f2b(p.x)|((u32)f2b(p.y)<<16);
      A.u[1]=f2b(p.z)|((u32)f2b(p.w)<<16);
      A.u[2]=f2b(q.x)|((u32)f2b(q.y)<<16);
      A.u[3]=f2b(q.z)|((u32)f2b(q.w)<<16);
    } else {
      uint4 q=*(const uint4*)((const u16*)xin + (size_t)growC*K + k0);
      A.u[0]=q.x; A.u[1]=q.y; A.u[2]=q.z; A.u[3]=q.w;
    }
    if(BN){
      #pragma unroll
      for(int j=0;j<4;j++){
        float lo=b2f(A.u[j]&0xffff), hi=b2f(A.u[j]>>16);
        float2 c1=BB[k0+2*j], c2=BB[k0+2*j+1];
        lo=c1.x*lo+c1.y; lo = lo>0.f? lo : __expf(lo)-1.f;
        hi=c2.x*hi+c2.y; hi = hi>0.f? hi : __expf(hi)-1.f;
        A.u[j]=f2b(lo)|((u32)f2b(hi)<<16);
      }
    }
    #pragma unroll
    for(int nt=0;nt<NT;nt++){
      union{ uint4 q; short8 s8; } Bf;
      Bf.q = *(const uint4*)&WT[(nt*16+m)*KP + k0];
      acc[nt] = __builtin_amdgcn_mfma_f32_16x16x32_bf16(A.s8, Bf.s8, acc[nt], 0,0,0);
    }
  }
  u16* hr = &HROW[wv*16*RS];
  #pragma unroll
  for(int nt=0;nt<NT;nt++){
    #pragma unroll
    for(int reg=0;reg<4;reg++)
      hr[(quad*4+reg)*RS + nt*16+m] = f2b(acc[nt][reg]);
  }
  __syncthreads();
  {
    int row=lane&15, task=quad, head=task&1, sd=task>>1;
    float p=0.f;
    const u16* hrow=&hr[row*RS + head*HID];
    const float* av=&AVb[sd*OUTC + head*HID];
    #pragma unroll 8
    for(int c=0;c<HID;c++) p += b2f(hrow[c])*av[c];
    int grow=grow0+row;
    if(grow<NNODES){ (sd? adst:asrc)[grow*2+head]=p; }
  }
  {
    constexpr int CH8 = OUTC/8;
    for(int idx=lane; idx<16*CH8; idx+=64){
      int rr=idx/CH8, c8=idx-rr*CH8;
      int grow=grow0+rr;
      if(grow<NNODES){
        int p, half;
        if constexpr (OUTC==80){
          if(c8<5){ p=c8; half=0; } else { p=c8-5; half=1; }
        } else {
          p = c8>>1; half = c8&1;
        }
        *(uint4*)(hout + ((size_t)p*NND + grow)*16 + half*8) = *(const uint4*)&hr[rr*RS + c8*8];
      }
    }
  }
}

// ---------------- fused softmax + gather-aggregate (plane passes) ----------
// Block = 256 threads = 128 dsts (2 lanes/dst). Loops cb over NCB planes;
// all resident blocks walk one 3.2MB plane at a time -> L2-resident gathers.
// Per cb: software-pipelined 4-edge stages (uint4 16B gather per lane).
// Non-final: lane writes its 8 channels (head split at ch 32).
// Final: planes are head-paired; lane0=head0, lane1=head1; mean via shfl_xor.
template<int NCB, bool FINAL>
__global__ __launch_bounds__(256) void k_aggf(
  const int* __restrict__ row_ptr, const int* __restrict__ col,
  const u16* __restrict__ hpl, const float2* __restrict__ asrc2,
  const float2* __restrict__ adst2, const void* __restrict__ bias,
  u16* __restrict__ houtb, void* __restrict__ outv, const int* __restrict__ flagp)
{
  const int f = flagp[0];
  int t = threadIdx.x;
  int g  = t>>1;            // dst group within block, 0..127
  int cl = t&1;             // lane within pair (channel half)
  int rr = blockIdx.x & 7, jb = blockIdx.x >> 3;
  bool ok = (jb*128 + g) < RSIZE;
  int d = rr*RSIZE + jb*128 + g;
  int base=0, deg=0;
  float2 adv = make_float2(0.f,0.f);
  if(ok){
    base = row_ptr[d];
    deg  = row_ptr[d+1] - base;
    adv  = adst2[d];
  }
  const int* cp = col + base;

  for(int cb=0; cb<NCB; ++cb){
    const u16* hp = hpl + ((size_t)cb*NND)*16 + cl*8;   // lane's 16B slice
    bool up0 = FINAL ? (cl==0) : ((cb*16 + cl*8) < 32); // head0 uses p0
    float acc[8]={0,0,0,0,0,0,0,0};
    float s0=0.f, s1=0.f;

    int    cA[4]={0,0,0,0}, cB[4]={0,0,0,0};
    float2 aA[4]={}, aB[4]={};
    uint4  hA4[4]={}, hB4[4]={};

#define LDBLK(JJ, C, A, H) do{ int lm_=deg-1; \
    C[0]=cp[((JJ)  <lm_)?(JJ)  :lm_]; C[1]=cp[((JJ)+1<lm_)?(JJ)+1:lm_]; \
    C[2]=cp[((JJ)+2<lm_)?(JJ)+2:lm_]; C[3]=cp[((JJ)+3<lm_)?(JJ)+3:lm_]; \
    A[0]=asrc2[C[0]]; A[1]=asrc2[C[1]]; A[2]=asrc2[C[2]]; A[3]=asrc2[C[3]]; \
    H[0]=*(const uint4*)(hp+(size_t)C[0]*16); \
    H[1]=*(const uint4*)(hp+(size_t)C[1]*16); \
    H[2]=*(const uint4*)(hp+(size_t)C[2]*16); \
    H[3]=*(const uint4*)(hp+(size_t)C[3]*16); \
  }while(0)

#define COMP4(J, A, H) do{ \
    _Pragma("unroll") \
    for(int k_=0;k_<4;k_++){ \
      bool vv = (J)+k_ < deg; \
      float e0=A[k_].x+adv.x; e0=fmaxf(e0,NEG_SLOPE*e0); e0=fminf(e0,60.f); \
      float e1=A[k_].y+adv.y; e1=fmaxf(e1,NEG_SLOPE*e1); e1=fminf(e1,60.f); \
      float p0=__expf(e0), p1=__expf(e1); \
      if(!vv){p0=0.f;p1=0.f;} \
      s0+=p0; s1+=p1; \
      float pc=up0?p0:p1; \
      acc[0]+=pc*blo(H[k_].x); acc[1]+=pc*bhi(H[k_].x); \
      acc[2]+=pc*blo(H[k_].y); acc[3]+=pc*bhi(H[k_].y); \
      acc[4]+=pc*blo(H[k_].z); acc[5]+=pc*bhi(H[k_].z); \
      acc[6]+=pc*blo(H[k_].w); acc[7]+=pc*bhi(H[k_].w); \
    } \
  }while(0)

    if(deg>0) LDBLK(0, cA, aA, hA4);
    for(int j=0;j<deg;j+=4){
      if(j+4<deg) LDBLK(j+4, cB, aB, hB4);   // next stage in flight
      COMP4(j, aA, hA4);
      #pragma unroll
      for(int k_=0;k_<4;k_++){ cA[k_]=cB[k_]; aA[k_]=aB[k_]; hA4[k_]=hB4[k_]; }
    }
#undef LDBLK
#undef COMP4

    float inv0 = s0>0.f?1.f/s0:0.f, inv1 = s1>0.f?1.f/s1:0.f;
    if(!FINAL){
      if(ok){
        int ch0 = cb*16 + cl*8;
        float inv = up0 ? inv0 : inv1;
        u16 o8[8];
        #pragma unroll
        for(int k=0;k<8;k++) o8[k]=f2b(acc[k]*inv + ldf(bias,ch0+k,f));
        uint4 ov;
        ov.x=(u32)o8[0]|((u32)o8[1]<<16); ov.y=(u32)o8[2]|((u32)o8[3]<<16);
        ov.z=(u32)o8[4]|((u32)o8[5]<<16); ov.w=(u32)o8[6]|((u32)o8[7]<<16);
        *(uint4*)(houtb + (size_t)d*64 + ch0) = ov;
      }
    } else {
      // plane cb covers out-ch [cb*8, cb*8+8): lane0 head0, lane1 head1
      float inv = cl ? inv1 : inv0;
      float nk[8], pk[8];
      #pragma unroll
      for(int k=0;k<8;k++) nk[k]=acc[k]*inv;
      #pragma unroll
      for(int k=0;k<8;k++) pk[k]=__shfl_xor(nk[k],1,64);
      if(ok && cl==0){
        float res[8];
        #pragma unroll
        for(int k=0;k<8;k++) res[k]=0.5f*(nk[k]+pk[k]) + ldf(bias,cb*8+k,f);
        if(f){
          float* op=((float*)outv) + (size_t)d*40 + cb*8;
          float4 w0=make_float4(res[0],res[1],res[2],res[3]);
          float4 w1=make_float4(res[4],res[5],res[6],res[7]);
          *(float4*)op = w0; *(float4*)(op+4) = w1;
        } else {
          u16 o8[8];
          #pragma unroll
          for(int k=0;k<8;k++) o8[k]=f2b(res[k]);
          uint4 ov;
          ov.x=(u32)o8[0]|((u32)o8[1]<<16); ov.y=(u32)o8[2]|((u32)o8[3]<<16);
          ov.z=(u32)o8[4]|((u32)o8[5]<<16); ov.w=(u32)o8[6]|((u32)o8[7]<<16);
          *(uint4*)(((u16*)outv) + (size_t)d*40 + cb*8) = ov;
        }
      }
    }
  }
}

// ---------------- batch norm (stats + coefficient finalize) ---------------
__global__ __launch_bounds__(256) void k_bnstats(const u16* __restrict__ h, float* __restrict__ stats){
  __shared__ float red[4][128];
  int t=threadIdx.x; int c=t&63; int g=t>>6;
  float s=0.f,q=0.f;
  for(int r=blockIdx.x*4+g; r<NNODES; r+=gridDim.x*4){
    float v=b2f(h[(size_t)r*64+c]); s+=v; q+=v*v;
  }
  red[g][c]=s; red[g][64+c]=q;
  __syncthreads();
  if(t<128){
    float tot=red[0][t]+red[1][t]+red[2][t]+red[3][t];
    atomicAdd(&stats[t], tot);
  }
}

__global__ void k_bnfinal(const float* __restrict__ stats,
                          const void* __restrict__ gm, const void* __restrict__ bt,
                          float2* __restrict__ bnab, const int* __restrict__ flagp){
  const int f = flagp[0];
  int c=threadIdx.x;
  if(c>=64) return;
  float mu=stats[c]*(1.0f/NNODES);
  float var=stats[64+c]*(1.0f/NNODES)-mu*mu;
  var = var>0.f?var:0.f;
  float A = ldf(gm,c,f)*rsqrtf(var+BN_EPS);
  float B = ldf(bt,c,f) - A*mu;
  bnab[c]=make_float2(A,B);
}

extern "C" void kernel_launch(void* const* d_in, const int* in_sizes, int n_in,
                              void* d_out, int out_size, void* d_ws, size_t ws_size,
                              hipStream_t stream){
  const void* x  =d_in[0];
  const int* ei =(const int*)d_in[1];
  const void* W0 =d_in[2];  const void* as0=d_in[3];  const void* ad0=d_in[4];
  const void* b0 =d_in[5];  const void* g0 =d_in[6];  const void* bt0=d_in[7];
  const void* W1 =d_in[8];  const void* as1=d_in[9];  const void* ad1=d_in[10];
  const void* b1 =d_in[11]; const void* g1 =d_in[12]; const void* bt1=d_in[13];
  const void* W2 =d_in[14]; const void* as2=d_in[15]; const void* ad2=d_in[16];
  const void* b2 =d_in[17];

  char* ws=(char*)d_ws;
  size_t off=0;
  auto alloc=[&](size_t bytes)->void*{ void* p=ws+off; off+=(bytes+255)&~(size_t)255; return p; };
  int*    flag   =(int*)   alloc(256);
  int*    row_ptr=(int*)   alloc((size_t)(NNODES+1)*4);
  int*    cnt    =(int*)   alloc((size_t)NNODES*4);
  int*    colx   =(int*)   alloc((size_t)ENTOT*4);
  int*    bsum   =(int*)   alloc((size_t)SCAN_NB*4);
  int*    gptr   =(int*)   alloc(256);
  u32*    bkt    =(u32*)   alloc((size_t)NRANGE*BCAP*4);
  u16*    hA     =(u16*)   alloc((size_t)NND*80*2);     // plane buffer; aliased as lhist during CSR build
  u16*    hB0    =(u16*)   alloc((size_t)NND*64*2);
  u16*    hB1    =(u16*)   alloc((size_t)NND*64*2);
  float*  asrc   =(float*) alloc((size_t)NNODES*2*4);
  float*  adst   =(float*) alloc((size_t)NNODES*2*4);
  float*  stats  =(float*) alloc(128*4);
  float2* bnab   =(float2*)alloc(64*8);
  int*    lhist  =(int*)hA;   // 12.8 MB needed, hA is 16 MB; dead before gemm L0

  k_detect<<<1,256,0,stream>>>((const u16*)x, flag);

  // CSR: partition -> LDS hist -> chunk scan -> row_ptr scan -> LDS scatter
  (void)hipMemsetAsync(gptr,0,256,stream);
  k_part2  <<<PBLK,256,0,stream>>>(ei,gptr,bkt);
  k_hist4  <<<NRANGE*NB2,256,0,stream>>>(bkt,gptr,lhist);
  k_sumscan<<<(NNODES+255)/256,256,0,stream>>>(lhist,cnt);
  k_scan_a <<<SCAN_NB,256,0,stream>>>(cnt,bsum);
  k_scan_b <<<1,64,0,stream>>>(bsum);
  k_scan_c <<<SCAN_NB,256,0,stream>>>(cnt,bsum,row_ptr);
  k_scatter4<<<NRANGE*NB2,256,0,stream>>>(bkt,gptr,row_ptr,lhist,colx);

  int gG = (NNODES+63)/64;                 // 1563
  int gA = NRANGE * ((RSIZE + 127)/128);   // 8 x 98 = 784 (128 dsts/block)
  // ---- layer 0 ----
  k_gemm_mfma<128,64,32,true ,false><<<gG,256,0,stream>>>(
      x,W0,as0,ad0,nullptr,hA,asrc,adst,flag);
  k_aggf<4,false><<<gA,256,0,stream>>>(row_ptr,colx,hA,
      (const float2*)asrc,(const float2*)adst,b0,hB0,nullptr,flag);
  (void)hipMemsetAsync(stats,0,512,stream);
  k_bnstats<<<256,256,0,stream>>>(hB0,stats);
  k_bnfinal<<<1,64,0,stream>>>(stats,g0,bt0,bnab,flag);
  // ---- layer 1 ----
  k_gemm_mfma<64,64,32,false,true ><<<gG,256,0,stream>>>(
      hB0,W1,as1,ad1,bnab,hA,asrc,adst,flag);
  k_aggf<4,false><<<gA,256,0,stream>>>(row_ptr,colx,hA,
      (const float2*)asrc,(const float2*)adst,b1,hB1,nullptr,flag);
  (void)hipMemsetAsync(stats,0,512,stream);
  k_bnstats<<<256,256,0,stream>>>(hB1,stats);
  k_bnfinal<<<1,64,0,stream>>>(stats,g1,bt1,bnab,flag);
  // ---- layer 2 (head-paired planes -> head mean -> d_out) ----
  k_gemm_mfma<64,80,40,false,true ><<<gG,256,0,stream>>>(
      hB1,W2,as2,ad2,bnab,hA,asrc,adst,flag);
  k_aggf<5,true ><<<gA,256,0,stream>>>(row_ptr,colx,hA,
      (const float2*)asrc,(const float2*)adst,b2,nullptr,d_out,flag);

  (void)in_sizes;(void)n_in;(void)out_size;(void)ws_size;
}

// Round 5
// 525.523 us; speedup vs baseline: 1.3002x; 1.3002x over previous
//
#include <hip/hip_runtime.h>
#include <hip/hip_bf16.h>
#include <math.h>

// GAT: N=100000 nodes, E=1600000 edges (+N self loops), 3 layers.
// Inputs bf16 (runtime-detected flag kept). Intermediates bf16.
// CSR build: atomic-free counting sort (8 dst-range buckets) + per-dst
// src-bin re-sort (k_binsort: 8 bins of 12500 src nodes, byte-packed
// counters). Aggregation: 8 dsts per wave (8 lanes/dst, 8ch/lane),
// 8 src-window PHASES with block-wide barriers -> all gathers in a phase
// hit a 1.6MB L2-resident hin window. XCD-swizzled blocks.

#define NNODES 100000
#define NEDGES 1600000
#define ENTOT  (NEDGES + NNODES)
#define NEG_SLOPE 0.2f
#define BN_EPS 1e-5f

#define NRANGE 8
#define RSIZE  (NNODES/NRANGE)     // 12500 (also src-bin size)
#define BCAP   262144              // per-bucket capacity (mean 212.5k)
#define PBLK   2048                // partition blocks
#define NB2    32                  // chunks per range

typedef unsigned short u16;
typedef unsigned int u32;
typedef unsigned long long u64;
typedef __attribute__((ext_vector_type(8))) short short8;
typedef __attribute__((ext_vector_type(4))) float f32x4;

__device__ __forceinline__ float b2f(u16 u){ union{u32 i; float f;} v; v.i=((u32)u)<<16; return v.f; }
__device__ __forceinline__ float blo(u32 u){ union{u32 i; float f;} v; v.i=u<<16; return v.f; }
__device__ __forceinline__ float bhi(u32 u){ union{u32 i; float f;} v; v.i=u&0xffff0000u; return v.f; }
__device__ __forceinline__ u16 f2b(float x){ __hip_bfloat16 b=__float2bfloat16(x); return *(u16*)&b; }
__device__ __forceinline__ float ldf(const void* p, int i, int f){
  return f ? ((const float*)p)[i] : b2f(((const u16*)p)[i]);
}

// ---------------- dtype probe ----------------
__global__ void k_detect(const u16* __restrict__ x, int* __restrict__ flag){
  __shared__ int bad;
  if(threadIdx.x==0) bad=0;
  __syncthreads();
  int cnt=0;
  for(int i=threadIdx.x;i<4096;i+=256){
    u16 v = x[2*i];
    int ex = (v>>7)&0xff;
    if(ex==0xff || (ex==0 && (v&0x7fff)!=0)) cnt++;
  }
  atomicAdd(&bad,cnt);
  __syncthreads();
  if(threadIdx.x==0) flag[0] = (bad>4)?1:0;   // 1 = fp32, 0 = bf16
}

// ---------------- pass A: partition edges into 8 dst-range buckets ---------
__global__ __launch_bounds__(256) void k_part2(
    const int* __restrict__ ei, int* __restrict__ gptr, u32* __restrict__ bkt){
  __shared__ int lcnt[NRANGE], gbase[NRANGE];
  int t=threadIdx.x;
  if(t<NRANGE) lcnt[t]=0;
  __syncthreads();
  const int CH=(ENTOT+PBLK-1)/PBLK;   // 831
  int beg=blockIdx.x*CH, end=beg+CH; if(end>ENTOT) end=ENTOT;
  int nd[4], ns[4], nr[4], ne=0;
  for(int i=beg+t; i<end; i+=256){
    int d=(i<NEDGES)? ei[NEDGES+i] : (i-NEDGES);
    int s=(i<NEDGES)? ei[i] : d;
    nd[ne]=d; ns[ne]=s; ne++;
  }
  #pragma unroll 4
  for(int k=0;k<ne;k++) nr[k]=atomicAdd(&lcnt[nd[k]/RSIZE],1);
  __syncthreads();
  if(t<NRANGE) gbase[t]=atomicAdd(&gptr[t],lcnt[t]);
  __syncthreads();
  #pragma unroll 4
  for(int k=0;k<ne;k++){
    int r=nd[k]/RSIZE;
    u32 e = ((u32)(nd[k]-r*RSIZE)<<17) | (u32)ns[k];   // dst_local(14b)|src(17b)
    __builtin_nontemporal_store(e, &bkt[(size_t)r*BCAP + gbase[r] + nr[k]]);
  }
}

// ---------------- pass B0: per-(range,chunk) LDS histogram -----------------
__global__ __launch_bounds__(256) void k_hist4(
    const u32* __restrict__ bkt, const int* __restrict__ gptr, int* __restrict__ lhist){
  __shared__ int lh[RSIZE];
  int t=threadIdx.x;
  for(int i=t;i<RSIZE;i+=256) lh[i]=0;
  __syncthreads();
  int r = blockIdx.x & (NRANGE-1);
  int c = blockIdx.x >> 3;
  int n = gptr[r];
  int per=(n+NB2-1)/NB2;
  int beg=c*per, end=beg+per; if(end>n) end=n;
  const u32* bp = bkt + (size_t)r*BCAP;
  for(int i=beg+t;i<end;i+=256) atomicAdd(&lh[bp[i]>>17],1);
  __syncthreads();
  int* out = lhist + (size_t)(r*NB2+c)*RSIZE;
  for(int i=t;i<RSIZE;i+=256) out[i]=lh[i];
}

// ---------------- node-wise chunk-scan: cnt + in-place exclusive scan ------
__global__ __launch_bounds__(256) void k_sumscan(int* __restrict__ lhist, int* __restrict__ cnt){
  int n = blockIdx.x*256 + threadIdx.x;
  if(n>=NNODES) return;
  int r = n/RSIZE, i = n - r*RSIZE;
  int* base = lhist + (size_t)r*NB2*RSIZE + i;
  int run=0;
  #pragma unroll 8
  for(int c=0;c<NB2;c++){
    int v = base[(size_t)c*RSIZE];
    base[(size_t)c*RSIZE] = run;
    run += v;
  }
  cnt[n]=run;
}

// ---------------- prefix scan (row_ptr) ----------------
#define SCAN_M (NNODES+1)
#define SCAN_NB ((SCAN_M + 2047)/2048)

__global__ void k_scan_a(const int* __restrict__ cnt, int* __restrict__ bsum){
  __shared__ int red[256];
  int b=blockIdx.x, t=threadIdx.x;
  int base = b*2048 + t*8;
  int s=0;
  #pragma unroll
  for(int j=0;j<8;j++){ int idx=base+j; s += (idx<NNODES)? cnt[idx]:0; }
  red[t]=s; __syncthreads();
  for(int o=128;o>0;o>>=1){ if(t<o) red[t]+=red[t+o]; __syncthreads(); }
  if(t==0) bsum[b]=red[0];
}

__global__ void k_scan_b(int* bsum){
  if(threadIdx.x==0){
    int run=0;
    for(int i=0;i<SCAN_NB;i++){ int v=bsum[i]; bsum[i]=run; run+=v; }
  }
}

__global__ void k_scan_c(const int* __restrict__ cnt, const int* __restrict__ bsum,
                         int* __restrict__ row_ptr){
  __shared__ int lds[256];
  int b=blockIdx.x, t=threadIdx.x;
  int base=b*2048+t*8;
  int v[8]; int s=0;
  #pragma unroll
  for(int j=0;j<8;j++){ int idx=base+j; int x=(idx<NNODES)?cnt[idx]:0; v[j]=s; s+=x; }
  lds[t]=s; __syncthreads();
  for(int o=1;o<256;o<<=1){
    int other=0; if(t>=o) other=lds[t-o];
    __syncthreads();
    lds[t]+=other;
    __syncthreads();
  }
  int texcl = lds[t] - s;
  int off0 = bsum[b] + texcl;
  #pragma unroll
  for(int j=0;j<8;j++){ int idx=base+j; if(idx<SCAN_M) row_ptr[idx]=off0+v[j]; }
}

// ---------------- pass B1: LDS-offset scatter (no global atomics) ----------
__global__ __launch_bounds__(256) void k_scatter4(
    const u32* __restrict__ bkt, const int* __restrict__ gptr,
    const int* __restrict__ row_ptr, const int* __restrict__ lhist,
    int* __restrict__ col){
  __shared__ int lofs[RSIZE];
  int t=threadIdx.x;
  int r = blockIdx.x & (NRANGE-1);
  int c = blockIdx.x >> 3;
  int lo = r*RSIZE;
  const int* cb = lhist + (size_t)(r*NB2+c)*RSIZE;
  for(int i=t;i<RSIZE;i+=256) lofs[i] = row_ptr[lo+i] + cb[i];
  __syncthreads();
  int n = gptr[r];
  int per=(n+NB2-1)/NB2;
  int beg=c*per, end=beg+per; if(end>n) end=n;
  const u32* bp = bkt + (size_t)r*BCAP;
  for(int i=beg+t;i<end;i+=256){
    u32 e=bp[i];
    int pos=atomicAdd(&lofs[e>>17],1);
    col[pos]=(int)(e & 0x1FFFF);
  }
}

// ---------------- per-dst src-bin re-sort --------------------------------
// One thread per dst: count 8 src-bins (byte-packed u64, deg<256),
// exclusive prefix, write bin starts subo[d][8], re-scatter col -> col2
// so each dst's list is grouped by src bin (12500-node windows).
__global__ __launch_bounds__(256) void k_binsort(
    const int* __restrict__ row_ptr, const int* __restrict__ col,
    int* __restrict__ col2, int* __restrict__ subo){
  int d = blockIdx.x*256 + threadIdx.x;
  if(d>=NNODES) return;
  int b0=row_ptr[d], b1=row_ptr[d+1];
  u64 cntp=0;
  for(int j=b0;j<b1;j++){
    int sb = col[j]/RSIZE;
    cntp += 1ull << (sb*8);
  }
  u64 offp=0; u32 run=0;
  #pragma unroll
  for(int sb=0;sb<8;sb++){
    offp |= (u64)(run&0xffu) << (sb*8);
    run += (u32)((cntp >> (sb*8)) & 0xff);
  }
  int s[8];
  #pragma unroll
  for(int sb=0;sb<8;sb++) s[sb] = b0 + (int)((offp>>(sb*8))&0xff);
  *(int4*)&subo[(size_t)d*8]   = make_int4(s[0],s[1],s[2],s[3]);
  *(int4*)&subo[(size_t)d*8+4] = make_int4(s[4],s[5],s[6],s[7]);
  for(int j=b0;j<b1;j++){
    int c = col[j];
    int sb = c/RSIZE;
    int pos = b0 + (int)((offp>>(sb*8))&0xff);
    offp += 1ull << (sb*8);
    col2[pos]=c;
  }
}

// ---------------- MFMA GEMM + fused BN/ELU + alpha epilogue ----------------
template<int K, int OUTC, int HID, bool XEXT, bool BN>
__global__ __launch_bounds__(256) void k_gemm_mfma(
    const void* __restrict__ xin, const void* __restrict__ W,
    const void* __restrict__ avs, const void* __restrict__ avd,
    const float2* __restrict__ bnab,
    u16* __restrict__ hout, float* __restrict__ asrc, float* __restrict__ adst,
    const int* __restrict__ flagp)
{
  const int f = flagp[0];
  constexpr int KP = K+8;          // WT row stride (u16), 16B-aligned rows
  constexpr int RS = OUTC+8;       // HROW row stride (u16)
  constexpr int NT = OUTC/16;      // col tiles per wave
  constexpr int KQ = K/32;         // mfma K steps
  __shared__ __align__(16) u16 WT[OUTC*KP];
  __shared__ __align__(16) u16 HROW[4*16*RS];
  __shared__ float AVb[2*OUTC];
  __shared__ float2 BB[K];
  int t=threadIdx.x;
  const u16* Wu=(const u16*)W; const float* Wf=(const float*)W;
  for(int i8=t*8; i8<K*OUTC; i8+=256*8){
    int k=i8/OUTC, c0=i8-k*OUTC;     // OUTC divisible by 8 -> row-local
    u16 w8[8];
    if(f){
      const float* wp=Wf+i8;
      float4 a=*(const float4*)wp, b=*(const float4*)(wp+4);
      w8[0]=f2b(a.x);w8[1]=f2b(a.y);w8[2]=f2b(a.z);w8[3]=f2b(a.w);
      w8[4]=f2b(b.x);w8[5]=f2b(b.y);w8[6]=f2b(b.z);w8[7]=f2b(b.w);
    } else {
      uint4 q=*(const uint4*)(Wu+i8);
      w8[0]=q.x&0xffff;w8[1]=q.x>>16;w8[2]=q.y&0xffff;w8[3]=q.y>>16;
      w8[4]=q.z&0xffff;w8[5]=q.z>>16;w8[6]=q.w&0xffff;w8[7]=q.w>>16;
    }
    #pragma unroll
    for(int u=0;u<8;u++) WT[(c0+u)*KP + k] = w8[u];
  }
  for(int idx=t; idx<2*OUTC; idx+=256)
    AVb[idx] = (idx<OUTC)? ldf(avs,idx,f) : ldf(avd,idx-OUTC,f);
  if(BN) for(int idx=t; idx<K; idx+=256) BB[idx]=bnab[idx];
  __syncthreads();

  int wv=t>>6, lane=t&63;
  int m=lane&15, quad=lane>>4;
  int grow0 = blockIdx.x*64 + wv*16;
  int growA = grow0 + m;
  bool avalid = growA < NNODES;
  int growC = avalid ? growA : 0;

  f32x4 acc[NT] = {};
  #pragma unroll
  for(int kq=0;kq<KQ;kq++){
    int k0 = kq*32 + quad*8;
    union{ u32 u[4]; short8 s8; } A;
    if(XEXT && f==1){
      const float* xr=(const float*)xin + (size_t)growC*K + k0;
      float4 p=*(const float4*)xr, q=*(const float4*)(xr+4);
      A.u[0]=f2b(p.x)|((u32)f2b(p.y)<<16);
      A.u[1]=f2b(p.z)|((u32)f2b(p.w)<<16);
      A.u[2]=f2b(q.x)|((u32)f2b(q.y)<<16);
      A.u[3]=f2b(q.z)|((u32)f2b(q.w)<<16);
    } else {
      uint4 q=*(const uint4*)((const u16*)xin + (size_t)growC*K + k0);
      A.u[0]=q.x; A.u[1]=q.y; A.u[2]=q.z; A.u[3]=q.w;
    }
    if(BN){
      #pragma unroll
      for(int j=0;j<4;j++){
        float lo=b2f(A.u[j]&0xffff), hi=b2f(A.u[j]>>16);
        float2 c1=BB[k0+2*j], c2=BB[k0+2*j+1];
        lo=c1.x*lo+c1.y; lo = lo>0.f? lo : __expf(lo)-1.f;
        hi=c2.x*hi+c2.y; hi = hi>0.f? hi : __expf(hi)-1.f;
        A.u[j]=f2b(lo)|((u32)f2b(hi)<<16);
      }
    }
    #pragma unroll
    for(int nt=0;nt<NT;nt++){
      union{ uint4 q; short8 s8; } Bf;
      Bf.q = *(const uint4*)&WT[(nt*16+m)*KP + k0];
      acc[nt] = __builtin_amdgcn_mfma_f32_16x16x32_bf16(A.s8, Bf.s8, acc[nt], 0,0,0);
    }
  }
  u16* hr = &HROW[wv*16*RS];
  #pragma unroll
  for(int nt=0;nt<NT;nt++){
    #pragma unroll
    for(int reg=0;reg<4;reg++)
      hr[(quad*4+reg)*RS + nt*16+m] = f2b(acc[nt][reg]);
  }
  __syncthreads();
  {
    int row=lane&15, task=quad, head=task&1, sd=task>>1;
    float p=0.f;
    const u16* hrow=&hr[row*RS + head*HID];
    const float* av=&AVb[sd*OUTC + head*HID];
    #pragma unroll 8
    for(int c=0;c<HID;c++) p += b2f(hrow[c])*av[c];
    int grow=grow0+row;
    if(grow<NNODES){ (sd? adst:asrc)[grow*2+head]=p; }
  }
  {
    constexpr int CH8 = OUTC/8;
    for(int idx=lane; idx<16*CH8; idx+=64){
      int rr=idx/CH8, c8=idx-rr*CH8;
      int grow=grow0+rr;
      if(grow<NNODES)
        *(uint4*)(hout + (size_t)grow*OUTC + c8*8) = *(const uint4*)&hr[rr*RS + c8*8];
    }
  }
}

// ---------------- fused softmax + gather-aggregate (src-window phases) -----
// 8 dsts per wave: group g = tid>>3 (32 dsts/block), lane cg = tid&7 owns
// channels [cg*8, cg*8+8). Edge lists src-binned (k_binsort); kernel walks
// 8 phases with a block barrier between them so all concurrent gathers hit
// one 1.6MB hin window (L2-resident). Per-dst bin starts live one-per-lane
// (bs at lane cg) and are broadcast per phase via shfl. No cross-lane
// reduction. XCD-swizzled (range = blockIdx%8).
template<int OUTC, bool FINAL>
__global__ __launch_bounds__(256) void k_aggf(
  const int* __restrict__ row_ptr, const int* __restrict__ col2,
  const int* __restrict__ subo,
  const u16* __restrict__ hin, const float2* __restrict__ asrc2,
  const float2* __restrict__ adst2, const void* __restrict__ bias,
  u16* __restrict__ houtb, void* __restrict__ outv, const int* __restrict__ flagp)
{
  const int f = flagp[0];
  __shared__ float vbuf[FINAL?32:1][84];
  constexpr int HSPLIT = FINAL ? 5 : 4;   // cg<HSPLIT -> head0 channels
  int t = threadIdx.x;
  int g  = t>>3;            // dst group within block, 0..31
  int cg = t&7;             // channel group
  int lane = t&63;
  int gb = lane & 56;       // group base lane within wave
  int rr = blockIdx.x & 7, jb = blockIdx.x >> 3;
  int lim = RSIZE - jb*32;              // valid groups in this block
  bool ok = g < lim;
  int d = rr*RSIZE + jb*32 + g;
  int dend=0, bs=0;
  float2 adv = make_float2(0.f,0.f);
  if(ok){
    dend = row_ptr[d+1];
    adv  = adst2[d];
    bs   = subo[(size_t)d*8 + cg];   // absolute start of src-bin cg
  }
  const u16* hcg = hin + cg*8;          // per-lane channel base
  const u16* hxg = hin + 64 + cg*2;     // FINAL extra channels base
  float acc[8]={0,0,0,0,0,0,0,0}, accx0=0.f, accx1=0.f;
  float s0=0.f, s1=0.f;

  for(int sb=0; sb<8; ++sb){
    int beg = __shfl(bs, gb+sb, 64);
    int end = (sb<7)? __shfl(bs, gb+sb+1, 64) : dend;
    for(int j=beg; j<end; j+=2){
      int c0 = col2[j];
      bool v1 = (j+1)<end;
      int c1 = col2[v1 ? j+1 : j];
      float2 sa = asrc2[c0];
      float2 sv = asrc2[c1];
      const u16* hp0 = hcg + (size_t)c0*OUTC;
      const u16* hp1 = hcg + (size_t)c1*OUTC;
      uint4 h0 = *(const uint4*)hp0;
      uint4 h1 = *(const uint4*)hp1;
      float e0 = sa.x+adv.x; e0 = fmaxf(e0, NEG_SLOPE*e0); e0 = fminf(e0,60.f);
      float e1 = sa.y+adv.y; e1 = fmaxf(e1, NEG_SLOPE*e1); e1 = fminf(e1,60.f);
      float p0 = __expf(e0), p1 = __expf(e1);
      float q0 = sv.x+adv.x; q0 = fmaxf(q0, NEG_SLOPE*q0); q0 = fminf(q0,60.f);
      float q1 = sv.y+adv.y; q1 = fmaxf(q1, NEG_SLOPE*q1); q1 = fminf(q1,60.f);
      float r0 = __expf(q0), r1 = __expf(q1);
      if(!v1){ r0=0.f; r1=0.f; }
      s0 += p0 + r0; s1 += p1 + r1;
      float pa = (cg<HSPLIT)? p0 : p1;
      float pb = (cg<HSPLIT)? r0 : r1;
      acc[0] += pa*blo(h0.x) + pb*blo(h1.x);
      acc[1] += pa*bhi(h0.x) + pb*bhi(h1.x);
      acc[2] += pa*blo(h0.y) + pb*blo(h1.y);
      acc[3] += pa*bhi(h0.y) + pb*bhi(h1.y);
      acc[4] += pa*blo(h0.z) + pb*blo(h1.z);
      acc[5] += pa*bhi(h0.z) + pb*bhi(h1.z);
      acc[6] += pa*blo(h0.w) + pb*blo(h1.w);
      acc[7] += pa*bhi(h0.w) + pb*bhi(h1.w);
      if(FINAL){
        ushort2 ha = *(const ushort2*)(hxg + (size_t)c0*OUTC);
        ushort2 hb = *(const ushort2*)(hxg + (size_t)c1*OUTC);
        accx0 += p1*b2f(ha.x) + r1*b2f(hb.x);
        accx1 += p1*b2f(ha.y) + r1*b2f(hb.y);
      }
    }
    __syncthreads();   // phase barrier: keep block inside one src window
  }

  float inv0 = s0>0.f?1.f/s0:0.f, inv1 = s1>0.f?1.f/s1:0.f;
  if(!FINAL){
    if(ok){
      float inv = (cg<4)? inv0 : inv1;
      u16 o8[8];
      #pragma unroll
      for(int k=0;k<8;k++) o8[k]=f2b(acc[k]*inv + ldf(bias,cg*8+k,f));
      uint4 ov;
      ov.x=(u32)o8[0]|((u32)o8[1]<<16); ov.y=(u32)o8[2]|((u32)o8[3]<<16);
      ov.z=(u32)o8[4]|((u32)o8[5]<<16); ov.w=(u32)o8[6]|((u32)o8[7]<<16);
      *(uint4*)(houtb + (size_t)d*64 + cg*8) = ov;
    }
  } else {
    if(ok){
      #pragma unroll
      for(int k=0;k<8;k++)
        vbuf[g][cg*8+k] = acc[k]*((cg<5)?inv0:inv1);
      vbuf[g][64+cg*2]   = accx0*inv1;
      vbuf[g][64+cg*2+1] = accx1*inv1;
    }
    __syncthreads();
    for(int idx=t; idx<32*40; idx+=256){
      int gg=idx/40, ch=idx-gg*40;
      if(gg<lim){
        int dd = rr*RSIZE + jb*32 + gg;
        float res = 0.5f*(vbuf[gg][ch] + vbuf[gg][40+ch]) + ldf(bias,ch,f);
        if(f) ((float*)outv)[(size_t)dd*40+ch] = res;
        else  ((__hip_bfloat16*)outv)[(size_t)dd*40+ch] = __float2bfloat16(res);
      }
    }
  }
}

// ---------------- batch norm (stats + coefficient finalize) ---------------
__global__ __launch_bounds__(256) void k_bnstats(const u16* __restrict__ h, float* __restrict__ stats){
  __shared__ float red[4][128];
  int t=threadIdx.x; int c=t&63; int g=t>>6;
  float s=0.f,q=0.f;
  for(int r=blockIdx.x*4+g; r<NNODES; r+=gridDim.x*4){
    float v=b2f(h[(size_t)r*64+c]); s+=v; q+=v*v;
  }
  red[g][c]=s; red[g][64+c]=q;
  __syncthreads();
  if(t<128){
    float tot=red[0][t]+red[1][t]+red[2][t]+red[3][t];
    atomicAdd(&stats[t], tot);
  }
}

__global__ void k_bnfinal(const float* __restrict__ stats,
                          const void* __restrict__ gm, const void* __restrict__ bt,
                          float2* __restrict__ bnab, const int* __restrict__ flagp){
  const int f = flagp[0];
  int c=threadIdx.x;
  if(c>=64) return;
  float mu=stats[c]*(1.0f/NNODES);
  float var=stats[64+c]*(1.0f/NNODES)-mu*mu;
  var = var>0.f?var:0.f;
  float A = ldf(gm,c,f)*rsqrtf(var+BN_EPS);
  float B = ldf(bt,c,f) - A*mu;
  bnab[c]=make_float2(A,B);
}

extern "C" void kernel_launch(void* const* d_in, const int* in_sizes, int n_in,
                              void* d_out, int out_size, void* d_ws, size_t ws_size,
                              hipStream_t stream){
  const void* x  =d_in[0];
  const int* ei =(const int*)d_in[1];
  const void* W0 =d_in[2];  const void* as0=d_in[3];  const void* ad0=d_in[4];
  const void* b0 =d_in[5];  const void* g0 =d_in[6];  const void* bt0=d_in[7];
  const void* W1 =d_in[8];  const void* as1=d_in[9];  const void* ad1=d_in[10];
  const void* b1 =d_in[11]; const void* g1 =d_in[12]; const void* bt1=d_in[13];
  const void* W2 =d_in[14]; const void* as2=d_in[15]; const void* ad2=d_in[16];
  const void* b2 =d_in[17];

  char* ws=(char*)d_ws;
  size_t off=0;
  auto alloc=[&](size_t bytes)->void*{ void* p=ws+off; off+=(bytes+255)&~(size_t)255; return p; };
  int*    flag   =(int*)   alloc(256);
  int*    row_ptr=(int*)   alloc((size_t)(NNODES+1)*4);
  int*    cnt    =(int*)   alloc((size_t)NNODES*4);
  int*    colx   =(int*)   alloc((size_t)ENTOT*4);
  int*    colx2  =(int*)   alloc((size_t)ENTOT*4);
  int*    subo   =(int*)   alloc((size_t)NNODES*8*4);
  int*    bsum   =(int*)   alloc((size_t)SCAN_NB*4);
  int*    gptr   =(int*)   alloc(256);
  u32*    bkt    =(u32*)   alloc((size_t)NRANGE*BCAP*4);
  u16*    hA     =(u16*)   alloc((size_t)100032*80*2);   // aliased as lhist during CSR build
  u16*    hB0    =(u16*)   alloc((size_t)100032*64*2);
  u16*    hB1    =(u16*)   alloc((size_t)100032*64*2);
  float*  asrc   =(float*) alloc((size_t)NNODES*2*4);
  float*  adst   =(float*) alloc((size_t)NNODES*2*4);
  float*  stats  =(float*) alloc(128*4);
  float2* bnab   =(float2*)alloc(64*8);
  int*    lhist  =(int*)hA;   // 12.8 MB needed, hA is 16 MB; dead before gemm L0

  k_detect<<<1,256,0,stream>>>((const u16*)x, flag);

  // CSR: partition -> LDS hist -> chunk scan -> row_ptr scan -> LDS scatter
  (void)hipMemsetAsync(gptr,0,256,stream);
  k_part2  <<<PBLK,256,0,stream>>>(ei,gptr,bkt);
  k_hist4  <<<NRANGE*NB2,256,0,stream>>>(bkt,gptr,lhist);
  k_sumscan<<<(NNODES+255)/256,256,0,stream>>>(lhist,cnt);
  k_scan_a <<<SCAN_NB,256,0,stream>>>(cnt,bsum);
  k_scan_b <<<1,64,0,stream>>>(bsum);
  k_scan_c <<<SCAN_NB,256,0,stream>>>(cnt,bsum,row_ptr);
  k_scatter4<<<NRANGE*NB2,256,0,stream>>>(bkt,gptr,row_ptr,lhist,colx);
  k_binsort<<<(NNODES+255)/256,256,0,stream>>>(row_ptr,colx,colx2,subo);

  int gG = (NNODES+63)/64;                 // 1563
  int gA = NRANGE * ((RSIZE + 31)/32);     // 8 x 391 = 3128 (32 dsts/block)
  // ---- layer 0 ----
  k_gemm_mfma<128,64,32,true ,false><<<gG,256,0,stream>>>(
      x,W0,as0,ad0,nullptr,hA,asrc,adst,flag);
  k_aggf<64,false><<<gA,256,0,stream>>>(row_ptr,colx2,subo,hA,
      (const float2*)asrc,(const float2*)adst,b0,hB0,nullptr,flag);
  (void)hipMemsetAsync(stats,0,512,stream);
  k_bnstats<<<256,256,0,stream>>>(hB0,stats);
  k_bnfinal<<<1,64,0,stream>>>(stats,g0,bt0,bnab,flag);
  // ---- layer 1 ----
  k_gemm_mfma<64,64,32,false,true ><<<gG,256,0,stream>>>(
      hB0,W1,as1,ad1,bnab,hA,asrc,adst,flag);
  k_aggf<64,false><<<gA,256,0,stream>>>(row_ptr,colx2,subo,hA,
      (const float2*)asrc,(const float2*)adst,b1,hB1,nullptr,flag);
  (void)hipMemsetAsync(stats,0,512,stream);
  k_bnstats<<<256,256,0,stream>>>(hB1,stats);
  k_bnfinal<<<1,64,0,stream>>>(stats,g1,bt1,bnab,flag);
  // ---- layer 2 (head mean -> d_out) ----
  k_gemm_mfma<64,80,40,false,true ><<<gG,256,0,stream>>>(
      hB1,W2,as2,ad2,bnab,hA,asrc,adst,flag);
  k_aggf<80,true ><<<gA,256,0,stream>>>(row_ptr,colx2,subo,hA,
      (const float2*)asrc,(const float2*)adst,b2,nullptr,d_out,flag);

  (void)in_sizes;(void)n_in;(void)out_size;(void)ws_size;
}

// Round 6
// 472.735 us; speedup vs baseline: 1.4453x; 1.1117x over previous
//
#include <hip/hip_runtime.h>
#include <hip/hip_bf16.h>
#include <math.h>

// GAT: N=100000 nodes, E=1600000 edges (+N self loops), 3 layers.
// Inputs bf16 (runtime-detected flag kept). Intermediates bf16.
// CSR build: atomic-free counting sort (8 dst-range buckets) + per-dst
// src-bin re-sort (k_binsort). Aggregation: 8 dsts per wave (8 lanes/dst,
// 8ch/lane), 8 BALANCED phases = equal eighths of each dst's bin-sorted
// list (same work per group per phase; segments track src windows) with
// block barriers -> concurrent gathers cluster in an L2-resident window
// without per-phase load imbalance. XCD-swizzled blocks.

#define NNODES 100000
#define NEDGES 1600000
#define ENTOT  (NEDGES + NNODES)
#define NEG_SLOPE 0.2f
#define BN_EPS 1e-5f

#define NRANGE 8
#define RSIZE  (NNODES/NRANGE)     // 12500 (also src-bin size)
#define BCAP   262144              // per-bucket capacity (mean 212.5k)
#define PBLK   2048                // partition blocks
#define NB2    32                  // chunks per range

typedef unsigned short u16;
typedef unsigned int u32;
typedef unsigned long long u64;
typedef __attribute__((ext_vector_type(8))) short short8;
typedef __attribute__((ext_vector_type(4))) float f32x4;

__device__ __forceinline__ float b2f(u16 u){ union{u32 i; float f;} v; v.i=((u32)u)<<16; return v.f; }
__device__ __forceinline__ float blo(u32 u){ union{u32 i; float f;} v; v.i=u<<16; return v.f; }
__device__ __forceinline__ float bhi(u32 u){ union{u32 i; float f;} v; v.i=u&0xffff0000u; return v.f; }
__device__ __forceinline__ u16 f2b(float x){ __hip_bfloat16 b=__float2bfloat16(x); return *(u16*)&b; }
__device__ __forceinline__ float ldf(const void* p, int i, int f){
  return f ? ((const float*)p)[i] : b2f(((const u16*)p)[i]);
}

// ---------------- dtype probe ----------------
__global__ void k_detect(const u16* __restrict__ x, int* __restrict__ flag){
  __shared__ int bad;
  if(threadIdx.x==0) bad=0;
  __syncthreads();
  int cnt=0;
  for(int i=threadIdx.x;i<4096;i+=256){
    u16 v = x[2*i];
    int ex = (v>>7)&0xff;
    if(ex==0xff || (ex==0 && (v&0x7fff)!=0)) cnt++;
  }
  atomicAdd(&bad,cnt);
  __syncthreads();
  if(threadIdx.x==0) flag[0] = (bad>4)?1:0;   // 1 = fp32, 0 = bf16
}

// ---------------- pass A: partition edges into 8 dst-range buckets ---------
__global__ __launch_bounds__(256) void k_part2(
    const int* __restrict__ ei, int* __restrict__ gptr, u32* __restrict__ bkt){
  __shared__ int lcnt[NRANGE], gbase[NRANGE];
  int t=threadIdx.x;
  if(t<NRANGE) lcnt[t]=0;
  __syncthreads();
  const int CH=(ENTOT+PBLK-1)/PBLK;   // 831
  int beg=blockIdx.x*CH, end=beg+CH; if(end>ENTOT) end=ENTOT;
  int nd[4], ns[4], nr[4], ne=0;
  for(int i=beg+t; i<end; i+=256){
    int d=(i<NEDGES)? ei[NEDGES+i] : (i-NEDGES);
    int s=(i<NEDGES)? ei[i] : d;
    nd[ne]=d; ns[ne]=s; ne++;
  }
  #pragma unroll 4
  for(int k=0;k<ne;k++) nr[k]=atomicAdd(&lcnt[nd[k]/RSIZE],1);
  __syncthreads();
  if(t<NRANGE) gbase[t]=atomicAdd(&gptr[t],lcnt[t]);
  __syncthreads();
  #pragma unroll 4
  for(int k=0;k<ne;k++){
    int r=nd[k]/RSIZE;
    u32 e = ((u32)(nd[k]-r*RSIZE)<<17) | (u32)ns[k];   // dst_local(14b)|src(17b)
    __builtin_nontemporal_store(e, &bkt[(size_t)r*BCAP + gbase[r] + nr[k]]);
  }
}

// ---------------- pass B0: per-(range,chunk) LDS histogram -----------------
__global__ __launch_bounds__(256) void k_hist4(
    const u32* __restrict__ bkt, const int* __restrict__ gptr, int* __restrict__ lhist){
  __shared__ int lh[RSIZE];
  int t=threadIdx.x;
  for(int i=t;i<RSIZE;i+=256) lh[i]=0;
  __syncthreads();
  int r = blockIdx.x & (NRANGE-1);
  int c = blockIdx.x >> 3;
  int n = gptr[r];
  int per=(n+NB2-1)/NB2;
  int beg=c*per, end=beg+per; if(end>n) end=n;
  const u32* bp = bkt + (size_t)r*BCAP;
  for(int i=beg+t;i<end;i+=256) atomicAdd(&lh[bp[i]>>17],1);
  __syncthreads();
  int* out = lhist + (size_t)(r*NB2+c)*RSIZE;
  for(int i=t;i<RSIZE;i+=256) out[i]=lh[i];
}

// ---------------- node-wise chunk-scan: cnt + in-place exclusive scan ------
__global__ __launch_bounds__(256) void k_sumscan(int* __restrict__ lhist, int* __restrict__ cnt){
  int n = blockIdx.x*256 + threadIdx.x;
  if(n>=NNODES) return;
  int r = n/RSIZE, i = n - r*RSIZE;
  int* base = lhist + (size_t)r*NB2*RSIZE + i;
  int run=0;
  #pragma unroll 8
  for(int c=0;c<NB2;c++){
    int v = base[(size_t)c*RSIZE];
    base[(size_t)c*RSIZE] = run;
    run += v;
  }
  cnt[n]=run;
}

// ---------------- prefix scan (row_ptr) ----------------
#define SCAN_M (NNODES+1)
#define SCAN_NB ((SCAN_M + 2047)/2048)

__global__ void k_scan_a(const int* __restrict__ cnt, int* __restrict__ bsum){
  __shared__ int red[256];
  int b=blockIdx.x, t=threadIdx.x;
  int base = b*2048 + t*8;
  int s=0;
  #pragma unroll
  for(int j=0;j<8;j++){ int idx=base+j; s += (idx<NNODES)? cnt[idx]:0; }
  red[t]=s; __syncthreads();
  for(int o=128;o>0;o>>=1){ if(t<o) red[t]+=red[t+o]; __syncthreads(); }
  if(t==0) bsum[b]=red[0];
}

__global__ void k_scan_b(int* bsum){
  if(threadIdx.x==0){
    int run=0;
    for(int i=0;i<SCAN_NB;i++){ int v=bsum[i]; bsum[i]=run; run+=v; }
  }
}

__global__ void k_scan_c(const int* __restrict__ cnt, const int* __restrict__ bsum,
                         int* __restrict__ row_ptr){
  __shared__ int lds[256];
  int b=blockIdx.x, t=threadIdx.x;
  int base=b*2048+t*8;
  int v[8]; int s=0;
  #pragma unroll
  for(int j=0;j<8;j++){ int idx=base+j; int x=(idx<NNODES)?cnt[idx]:0; v[j]=s; s+=x; }
  lds[t]=s; __syncthreads();
  for(int o=1;o<256;o<<=1){
    int other=0; if(t>=o) other=lds[t-o];
    __syncthreads();
    lds[t]+=other;
    __syncthreads();
  }
  int texcl = lds[t] - s;
  int off0 = bsum[b] + texcl;
  #pragma unroll
  for(int j=0;j<8;j++){ int idx=base+j; if(idx<SCAN_M) row_ptr[idx]=off0+v[j]; }
}

// ---------------- pass B1: LDS-offset scatter (no global atomics) ----------
__global__ __launch_bounds__(256) void k_scatter4(
    const u32* __restrict__ bkt, const int* __restrict__ gptr,
    const int* __restrict__ row_ptr, const int* __restrict__ lhist,
    int* __restrict__ col){
  __shared__ int lofs[RSIZE];
  int t=threadIdx.x;
  int r = blockIdx.x & (NRANGE-1);
  int c = blockIdx.x >> 3;
  int lo = r*RSIZE;
  const int* cb = lhist + (size_t)(r*NB2+c)*RSIZE;
  for(int i=t;i<RSIZE;i+=256) lofs[i] = row_ptr[lo+i] + cb[i];
  __syncthreads();
  int n = gptr[r];
  int per=(n+NB2-1)/NB2;
  int beg=c*per, end=beg+per; if(end>n) end=n;
  const u32* bp = bkt + (size_t)r*BCAP;
  for(int i=beg+t;i<end;i+=256){
    u32 e=bp[i];
    int pos=atomicAdd(&lofs[e>>17],1);
    col[pos]=(int)(e & 0x1FFFF);
  }
}

// ---------------- per-dst src-bin re-sort --------------------------------
// One thread per dst: count 8 src-bins (byte-packed u64, deg<256),
// exclusive prefix, re-scatter col -> col2 so each dst's list is grouped
// by src bin (ascending src windows).
__global__ __launch_bounds__(256) void k_binsort(
    const int* __restrict__ row_ptr, const int* __restrict__ col,
    int* __restrict__ col2){
  int d = blockIdx.x*256 + threadIdx.x;
  if(d>=NNODES) return;
  int b0=row_ptr[d], b1=row_ptr[d+1];
  u64 cntp=0;
  for(int j=b0;j<b1;j++){
    int sb = col[j]/RSIZE;
    cntp += 1ull << (sb*8);
  }
  u64 offp=0; u32 run=0;
  #pragma unroll
  for(int sb=0;sb<8;sb++){
    offp |= (u64)(run&0xffu) << (sb*8);
    run += (u32)((cntp >> (sb*8)) & 0xff);
  }
  for(int j=b0;j<b1;j++){
    int c = col[j];
    int sb = c/RSIZE;
    int pos = b0 + (int)((offp>>(sb*8))&0xff);
    offp += 1ull << (sb*8);
    col2[pos]=c;
  }
}

// ---------------- MFMA GEMM + fused BN/ELU + alpha epilogue ----------------
template<int K, int OUTC, int HID, bool XEXT, bool BN>
__global__ __launch_bounds__(256) void k_gemm_mfma(
    const void* __restrict__ xin, const void* __restrict__ W,
    const void* __restrict__ avs, const void* __restrict__ avd,
    const float2* __restrict__ bnab,
    u16* __restrict__ hout, float* __restrict__ asrc, float* __restrict__ adst,
    const int* __restrict__ flagp)
{
  const int f = flagp[0];
  constexpr int KP = K+8;          // WT row stride (u16), 16B-aligned rows
  constexpr int RS = OUTC+8;       // HROW row stride (u16)
  constexpr int NT = OUTC/16;      // col tiles per wave
  constexpr int KQ = K/32;         // mfma K steps
  __shared__ __align__(16) u16 WT[OUTC*KP];
  __shared__ __align__(16) u16 HROW[4*16*RS];
  __shared__ float AVb[2*OUTC];
  __shared__ float2 BB[K];
  int t=threadIdx.x;
  const u16* Wu=(const u16*)W; const float* Wf=(const float*)W;
  for(int i8=t*8; i8<K*OUTC; i8+=256*8){
    int k=i8/OUTC, c0=i8-k*OUTC;     // OUTC divisible by 8 -> row-local
    u16 w8[8];
    if(f){
      const float* wp=Wf+i8;
      float4 a=*(const float4*)wp, b=*(const float4*)(wp+4);
      w8[0]=f2b(a.x);w8[1]=f2b(a.y);w8[2]=f2b(a.z);w8[3]=f2b(a.w);
      w8[4]=f2b(b.x);w8[5]=f2b(b.y);w8[6]=f2b(b.z);w8[7]=f2b(b.w);
    } else {
      uint4 q=*(const uint4*)(Wu+i8);
      w8[0]=q.x&0xffff;w8[1]=q.x>>16;w8[2]=q.y&0xffff;w8[3]=q.y>>16;
      w8[4]=q.z&0xffff;w8[5]=q.z>>16;w8[6]=q.w&0xffff;w8[7]=q.w>>16;
    }
    #pragma unroll
    for(int u=0;u<8;u++) WT[(c0+u)*KP + k] = w8[u];
  }
  for(int idx=t; idx<2*OUTC; idx+=256)
    AVb[idx] = (idx<OUTC)? ldf(avs,idx,f) : ldf(avd,idx-OUTC,f);
  if(BN) for(int idx=t; idx<K; idx+=256) BB[idx]=bnab[idx];
  __syncthreads();

  int wv=t>>6, lane=t&63;
  int m=lane&15, quad=lane>>4;
  int grow0 = blockIdx.x*64 + wv*16;
  int growA = grow0 + m;
  bool avalid = growA < NNODES;
  int growC = avalid ? growA : 0;

  f32x4 acc[NT] = {};
  #pragma unroll
  for(int kq=0;kq<KQ;kq++){
    int k0 = kq*32 + quad*8;
    union{ u32 u[4]; short8 s8; } A;
    if(XEXT && f==1){
      const float* xr=(const float*)xin + (size_t)growC*K + k0;
      float4 p=*(const float4*)xr, q=*(const float4*)(xr+4);
      A.u[0]=f2b(p.x)|((u32)f2b(p.y)<<16);
      A.u[1]=f2b(p.z)|((u32)f2b(p.w)<<16);
      A.u[2]=f2b(q.x)|((u32)f2b(q.y)<<16);
      A.u[3]=f2b(q.z)|((u32)f2b(q.w)<<16);
    } else {
      uint4 q=*(const uint4*)((const u16*)xin + (size_t)growC*K + k0);
      A.u[0]=q.x; A.u[1]=q.y; A.u[2]=q.z; A.u[3]=q.w;
    }
    if(BN){
      #pragma unroll
      for(int j=0;j<4;j++){
        float lo=b2f(A.u[j]&0xffff), hi=b2f(A.u[j]>>16);
        float2 c1=BB[k0+2*j], c2=BB[k0+2*j+1];
        lo=c1.x*lo+c1.y; lo = lo>0.f? lo : __expf(lo)-1.f;
        hi=c2.x*hi+c2.y; hi = hi>0.f? hi : __expf(hi)-1.f;
        A.u[j]=f2b(lo)|((u32)f2b(hi)<<16);
      }
    }
    #pragma unroll
    for(int nt=0;nt<NT;nt++){
      union{ uint4 q; short8 s8; } Bf;
      Bf.q = *(const uint4*)&WT[(nt*16+m)*KP + k0];
      acc[nt] = __builtin_amdgcn_mfma_f32_16x16x32_bf16(A.s8, Bf.s8, acc[nt], 0,0,0);
    }
  }
  u16* hr = &HROW[wv*16*RS];
  #pragma unroll
  for(int nt=0;nt<NT;nt++){
    #pragma unroll
    for(int reg=0;reg<4;reg++)
      hr[(quad*4+reg)*RS + nt*16+m] = f2b(acc[nt][reg]);
  }
  __syncthreads();
  {
    int row=lane&15, task=quad, head=task&1, sd=task>>1;
    float p=0.f;
    const u16* hrow=&hr[row*RS + head*HID];
    const float* av=&AVb[sd*OUTC + head*HID];
    #pragma unroll 8
    for(int c=0;c<HID;c++) p += b2f(hrow[c])*av[c];
    int grow=grow0+row;
    if(grow<NNODES){ (sd? adst:asrc)[grow*2+head]=p; }
  }
  {
    constexpr int CH8 = OUTC/8;
    for(int idx=lane; idx<16*CH8; idx+=64){
      int rr=idx/CH8, c8=idx-rr*CH8;
      int grow=grow0+rr;
      if(grow<NNODES)
        *(uint4*)(hout + (size_t)grow*OUTC + c8*8) = *(const uint4*)&hr[rr*RS + c8*8];
    }
  }
}

// ---------------- fused softmax + gather-aggregate (balanced phases) -------
// 8 dsts per wave: group g = tid>>3 (32 dsts/block), lane cg = tid&7 owns
// channels [cg*8, cg*8+8). Edge lists src-bin-ordered (k_binsort); kernel
// walks 8 BALANCED phases (equal eighths of each dst's list) with block
// barriers: same work per group per phase (no imbalance), segments track
// ascending src windows (approx L2-resident). XCD-swizzled (blockIdx%8).
template<int OUTC, bool FINAL>
__global__ __launch_bounds__(256) void k_aggf(
  const int* __restrict__ row_ptr, const int* __restrict__ col2,
  const u16* __restrict__ hin, const float2* __restrict__ asrc2,
  const float2* __restrict__ adst2, const void* __restrict__ bias,
  u16* __restrict__ houtb, void* __restrict__ outv, const int* __restrict__ flagp)
{
  const int f = flagp[0];
  __shared__ float vbuf[FINAL?32:1][84];
  constexpr int HSPLIT = FINAL ? 5 : 4;   // cg<HSPLIT -> head0 channels
  int t = threadIdx.x;
  int g  = t>>3;            // dst group within block, 0..31
  int cg = t&7;             // channel group
  int rr = blockIdx.x & 7, jb = blockIdx.x >> 3;
  int lim = RSIZE - jb*32;              // valid groups in this block
  bool ok = g < lim;
  int d = rr*RSIZE + jb*32 + g;
  int base=0, deg=0;
  float2 adv = make_float2(0.f,0.f);
  if(ok){
    base = row_ptr[d];
    deg  = row_ptr[d+1] - base;
    adv  = adst2[d];
  }
  const int* cp  = col2 + base;
  const u16* hcg = hin + cg*8;          // per-lane channel base
  const u16* hxg = hin + 64 + cg*2;     // FINAL extra channels base
  float acc[8]={0,0,0,0,0,0,0,0}, accx0=0.f, accx1=0.f;
  float s0=0.f, s1=0.f;

  for(int ph=0; ph<8; ++ph){
    int beg = (deg*ph)>>3;
    int end = (deg*(ph+1))>>3;
    for(int j=beg; j<end; j+=2){
      int c0 = cp[j];
      bool v1 = (j+1)<end;
      int c1 = cp[v1 ? j+1 : j];
      float2 sa = asrc2[c0];
      float2 sv = asrc2[c1];
      const u16* hp0 = hcg + (size_t)c0*OUTC;
      const u16* hp1 = hcg + (size_t)c1*OUTC;
      uint4 h0 = *(const uint4*)hp0;
      uint4 h1 = *(const uint4*)hp1;
      float e0 = sa.x+adv.x; e0 = fmaxf(e0, NEG_SLOPE*e0); e0 = fminf(e0,60.f);
      float e1 = sa.y+adv.y; e1 = fmaxf(e1, NEG_SLOPE*e1); e1 = fminf(e1,60.f);
      float p0 = __expf(e0), p1 = __expf(e1);
      float q0 = sv.x+adv.x; q0 = fmaxf(q0, NEG_SLOPE*q0); q0 = fminf(q0,60.f);
      float q1 = sv.y+adv.y; q1 = fmaxf(q1, NEG_SLOPE*q1); q1 = fminf(q1,60.f);
      float r0 = __expf(q0), r1 = __expf(q1);
      if(!v1){ r0=0.f; r1=0.f; }
      s0 += p0 + r0; s1 += p1 + r1;
      float pa = (cg<HSPLIT)? p0 : p1;
      float pb = (cg<HSPLIT)? r0 : r1;
      acc[0] += pa*blo(h0.x) + pb*blo(h1.x);
      acc[1] += pa*bhi(h0.x) + pb*bhi(h1.x);
      acc[2] += pa*blo(h0.y) + pb*blo(h1.y);
      acc[3] += pa*bhi(h0.y) + pb*bhi(h1.y);
      acc[4] += pa*blo(h0.z) + pb*blo(h1.z);
      acc[5] += pa*bhi(h0.z) + pb*bhi(h1.z);
      acc[6] += pa*blo(h0.w) + pb*blo(h1.w);
      acc[7] += pa*bhi(h0.w) + pb*bhi(h1.w);
      if(FINAL){
        ushort2 ha = *(const ushort2*)(hxg + (size_t)c0*OUTC);
        ushort2 hb = *(const ushort2*)(hxg + (size_t)c1*OUTC);
        accx0 += p1*b2f(ha.x) + r1*b2f(hb.x);
        accx1 += p1*b2f(ha.y) + r1*b2f(hb.y);
      }
    }
    __syncthreads();   // phase barrier: keep block inside one src window
  }

  float inv0 = s0>0.f?1.f/s0:0.f, inv1 = s1>0.f?1.f/s1:0.f;
  if(!FINAL){
    if(ok){
      float inv = (cg<4)? inv0 : inv1;
      u16 o8[8];
      #pragma unroll
      for(int k=0;k<8;k++) o8[k]=f2b(acc[k]*inv + ldf(bias,cg*8+k,f));
      uint4 ov;
      ov.x=(u32)o8[0]|((u32)o8[1]<<16); ov.y=(u32)o8[2]|((u32)o8[3]<<16);
      ov.z=(u32)o8[4]|((u32)o8[5]<<16); ov.w=(u32)o8[6]|((u32)o8[7]<<16);
      *(uint4*)(houtb + (size_t)d*64 + cg*8) = ov;
    }
  } else {
    if(ok){
      #pragma unroll
      for(int k=0;k<8;k++)
        vbuf[g][cg*8+k] = acc[k]*((cg<5)?inv0:inv1);
      vbuf[g][64+cg*2]   = accx0*inv1;
      vbuf[g][64+cg*2+1] = accx1*inv1;
    }
    __syncthreads();
    for(int idx=t; idx<32*40; idx+=256){
      int gg=idx/40, ch=idx-gg*40;
      if(gg<lim){
        int dd = rr*RSIZE + jb*32 + gg;
        float res = 0.5f*(vbuf[gg][ch] + vbuf[gg][40+ch]) + ldf(bias,ch,f);
        if(f) ((float*)outv)[(size_t)dd*40+ch] = res;
        else  ((__hip_bfloat16*)outv)[(size_t)dd*40+ch] = __float2bfloat16(res);
      }
    }
  }
}

// ---------------- batch norm (stats + coefficient finalize) ---------------
__global__ __launch_bounds__(256) void k_bnstats(const u16* __restrict__ h, float* __restrict__ stats){
  __shared__ float red[4][128];
  int t=threadIdx.x; int c=t&63; int g=t>>6;
  float s=0.f,q=0.f;
  for(int r=blockIdx.x*4+g; r<NNODES; r+=gridDim.x*4){
    float v=b2f(h[(size_t)r*64+c]); s+=v; q+=v*v;
  }
  red[g][c]=s; red[g][64+c]=q;
  __syncthreads();
  if(t<128){
    float tot=red[0][t]+red[1][t]+red[2][t]+red[3][t];
    atomicAdd(&stats[t], tot);
  }
}

__global__ void k_bnfinal(const float* __restrict__ stats,
                          const void* __restrict__ gm, const void* __restrict__ bt,
                          float2* __restrict__ bnab, const int* __restrict__ flagp){
  const int f = flagp[0];
  int c=threadIdx.x;
  if(c>=64) return;
  float mu=stats[c]*(1.0f/NNODES);
  float var=stats[64+c]*(1.0f/NNODES)-mu*mu;
  var = var>0.f?var:0.f;
  float A = ldf(gm,c,f)*rsqrtf(var+BN_EPS);
  float B = ldf(bt,c,f) - A*mu;
  bnab[c]=make_float2(A,B);
}

extern "C" void kernel_launch(void* const* d_in, const int* in_sizes, int n_in,
                              void* d_out, int out_size, void* d_ws, size_t ws_size,
                              hipStream_t stream){
  const void* x  =d_in[0];
  const int* ei =(const int*)d_in[1];
  const void* W0 =d_in[2];  const void* as0=d_in[3];  const void* ad0=d_in[4];
  const void* b0 =d_in[5];  const void* g0 =d_in[6];  const void* bt0=d_in[7];
  const void* W1 =d_in[8];  const void* as1=d_in[9];  const void* ad1=d_in[10];
  const void* b1 =d_in[11]; const void* g1 =d_in[12]; const void* bt1=d_in[13];
  const void* W2 =d_in[14]; const void* as2=d_in[15]; const void* ad2=d_in[16];
  const void* b2 =d_in[17];

  char* ws=(char*)d_ws;
  size_t off=0;
  auto alloc=[&](size_t bytes)->void*{ void* p=ws+off; off+=(bytes+255)&~(size_t)255; return p; };
  int*    flag   =(int*)   alloc(256);
  int*    row_ptr=(int*)   alloc((size_t)(NNODES+1)*4);
  int*    cnt    =(int*)   alloc((size_t)NNODES*4);
  int*    colx   =(int*)   alloc((size_t)ENTOT*4);
  int*    colx2  =(int*)   alloc((size_t)ENTOT*4);
  int*    bsum   =(int*)   alloc((size_t)SCAN_NB*4);
  int*    gptr   =(int*)   alloc(256);
  u32*    bkt    =(u32*)   alloc((size_t)NRANGE*BCAP*4);
  u16*    hA     =(u16*)   alloc((size_t)100032*80*2);   // aliased as lhist during CSR build
  u16*    hB0    =(u16*)   alloc((size_t)100032*64*2);
  u16*    hB1    =(u16*)   alloc((size_t)100032*64*2);
  float*  asrc   =(float*) alloc((size_t)NNODES*2*4);
  float*  adst   =(float*) alloc((size_t)NNODES*2*4);
  float*  stats  =(float*) alloc(128*4);
  float2* bnab   =(float2*)alloc(64*8);
  int*    lhist  =(int*)hA;   // 12.8 MB needed, hA is 16 MB; dead before gemm L0

  k_detect<<<1,256,0,stream>>>((const u16*)x, flag);

  // CSR: partition -> LDS hist -> chunk scan -> row_ptr scan -> LDS scatter
  (void)hipMemsetAsync(gptr,0,256,stream);
  k_part2  <<<PBLK,256,0,stream>>>(ei,gptr,bkt);
  k_hist4  <<<NRANGE*NB2,256,0,stream>>>(bkt,gptr,lhist);
  k_sumscan<<<(NNODES+255)/256,256,0,stream>>>(lhist,cnt);
  k_scan_a <<<SCAN_NB,256,0,stream>>>(cnt,bsum);
  k_scan_b <<<1,64,0,stream>>>(bsum);
  k_scan_c <<<SCAN_NB,256,0,stream>>>(cnt,bsum,row_ptr);
  k_scatter4<<<NRANGE*NB2,256,0,stream>>>(bkt,gptr,row_ptr,lhist,colx);
  k_binsort<<<(NNODES+255)/256,256,0,stream>>>(row_ptr,colx,colx2);

  int gG = (NNODES+63)/64;                 // 1563
  int gA = NRANGE * ((RSIZE + 31)/32);     // 8 x 391 = 3128 (32 dsts/block)
  // ---- layer 0 ----
  k_gemm_mfma<128,64,32,true ,false><<<gG,256,0,stream>>>(
      x,W0,as0,ad0,nullptr,hA,asrc,adst,flag);
  k_aggf<64,false><<<gA,256,0,stream>>>(row_ptr,colx2,hA,
      (const float2*)asrc,(const float2*)adst,b0,hB0,nullptr,flag);
  (void)hipMemsetAsync(stats,0,512,stream);
  k_bnstats<<<256,256,0,stream>>>(hB0,stats);
  k_bnfinal<<<1,64,0,stream>>>(stats,g0,bt0,bnab,flag);
  // ---- layer 1 ----
  k_gemm_mfma<64,64,32,false,true ><<<gG,256,0,stream>>>(
      hB0,W1,as1,ad1,bnab,hA,asrc,adst,flag);
  k_aggf<64,false><<<gA,256,0,stream>>>(row_ptr,colx2,hA,
      (const float2*)asrc,(const float2*)adst,b1,hB1,nullptr,flag);
  (void)hipMemsetAsync(stats,0,512,stream);
  k_bnstats<<<256,256,0,stream>>>(hB1,stats);
  k_bnfinal<<<1,64,0,stream>>>(stats,g1,bt1,bnab,flag);
  // ---- layer 2 (head mean -> d_out) ----
  k_gemm_mfma<64,80,40,false,true ><<<gG,256,0,stream>>>(
      hB1,W2,as2,ad2,bnab,hA,asrc,adst,flag);
  k_aggf<80,true ><<<gA,256,0,stream>>>(row_ptr,colx2,hA,
      (const float2*)asrc,(const float2*)adst,b2,nullptr,d_out,flag);

  (void)in_sizes;(void)n_in;(void)out_size;(void)ws_size;
}

// Round 7
// 466.128 us; speedup vs baseline: 1.4658x; 1.0142x over previous
//
#include <hip/hip_runtime.h>
#include <hip/hip_bf16.h>
#include <math.h>

// GAT: N=100000 nodes, E=1600000 edges (+N self loops), 3 layers.
// Inputs bf16 (runtime-detected flag kept). Intermediates bf16.
// CSR build: atomic-free counting sort (8 dst-range buckets) + per-dst
// src-bin re-sort (k_binsort, LDS-staged). Aggregation: 8 dsts per wave
// (8 lanes/dst, 8ch/lane), 4 BALANCED phases (equal quarters of each dst's
// bin-sorted list -> ~3.2MB L2-resident src windows, low phase overhead).
// Non-final layers: single-exp per lane (own head only). XCD-swizzled.

#define NNODES 100000
#define NEDGES 1600000
#define ENTOT  (NEDGES + NNODES)
#define NEG_SLOPE 0.2f
#define BN_EPS 1e-5f

#define NRANGE 8
#define RSIZE  (NNODES/NRANGE)     // 12500 (also src-bin size)
#define BCAP   262144              // per-bucket capacity (mean 212.5k)
#define PBLK   2048                // partition blocks
#define NB2    32                  // chunks per range
#define BSL    8192                // binsort LDS staging (ints)

typedef unsigned short u16;
typedef unsigned int u32;
typedef unsigned long long u64;
typedef __attribute__((ext_vector_type(8))) short short8;
typedef __attribute__((ext_vector_type(4))) float f32x4;

__device__ __forceinline__ float b2f(u16 u){ union{u32 i; float f;} v; v.i=((u32)u)<<16; return v.f; }
__device__ __forceinline__ float blo(u32 u){ union{u32 i; float f;} v; v.i=u<<16; return v.f; }
__device__ __forceinline__ float bhi(u32 u){ union{u32 i; float f;} v; v.i=u&0xffff0000u; return v.f; }
__device__ __forceinline__ u16 f2b(float x){ __hip_bfloat16 b=__float2bfloat16(x); return *(u16*)&b; }
__device__ __forceinline__ float ldf(const void* p, int i, int f){
  return f ? ((const float*)p)[i] : b2f(((const u16*)p)[i]);
}

// ---------------- dtype probe ----------------
__global__ void k_detect(const u16* __restrict__ x, int* __restrict__ flag){
  __shared__ int bad;
  if(threadIdx.x==0) bad=0;
  __syncthreads();
  int cnt=0;
  for(int i=threadIdx.x;i<4096;i+=256){
    u16 v = x[2*i];
    int ex = (v>>7)&0xff;
    if(ex==0xff || (ex==0 && (v&0x7fff)!=0)) cnt++;
  }
  atomicAdd(&bad,cnt);
  __syncthreads();
  if(threadIdx.x==0) flag[0] = (bad>4)?1:0;   // 1 = fp32, 0 = bf16
}

// ---------------- pass A: partition edges into 8 dst-range buckets ---------
__global__ __launch_bounds__(256) void k_part2(
    const int* __restrict__ ei, int* __restrict__ gptr, u32* __restrict__ bkt){
  __shared__ int lcnt[NRANGE], gbase[NRANGE];
  int t=threadIdx.x;
  if(t<NRANGE) lcnt[t]=0;
  __syncthreads();
  const int CH=(ENTOT+PBLK-1)/PBLK;   // 831
  int beg=blockIdx.x*CH, end=beg+CH; if(end>ENTOT) end=ENTOT;
  int nd[4], ns[4], nr[4], ne=0;
  for(int i=beg+t; i<end; i+=256){
    int d=(i<NEDGES)? ei[NEDGES+i] : (i-NEDGES);
    int s=(i<NEDGES)? ei[i] : d;
    nd[ne]=d; ns[ne]=s; ne++;
  }
  #pragma unroll 4
  for(int k=0;k<ne;k++) nr[k]=atomicAdd(&lcnt[nd[k]/RSIZE],1);
  __syncthreads();
  if(t<NRANGE) gbase[t]=atomicAdd(&gptr[t],lcnt[t]);
  __syncthreads();
  #pragma unroll 4
  for(int k=0;k<ne;k++){
    int r=nd[k]/RSIZE;
    u32 e = ((u32)(nd[k]-r*RSIZE)<<17) | (u32)ns[k];   // dst_local(14b)|src(17b)
    __builtin_nontemporal_store(e, &bkt[(size_t)r*BCAP + gbase[r] + nr[k]]);
  }
}

// ---------------- pass B0: per-(range,chunk) LDS histogram -----------------
__global__ __launch_bounds__(256) void k_hist4(
    const u32* __restrict__ bkt, const int* __restrict__ gptr, int* __restrict__ lhist){
  __shared__ int lh[RSIZE];
  int t=threadIdx.x;
  for(int i=t;i<RSIZE;i+=256) lh[i]=0;
  __syncthreads();
  int r = blockIdx.x & (NRANGE-1);
  int c = blockIdx.x >> 3;
  int n = gptr[r];
  int per=(n+NB2-1)/NB2;
  int beg=c*per, end=beg+per; if(end>n) end=n;
  const u32* bp = bkt + (size_t)r*BCAP;
  for(int i=beg+t;i<end;i+=256) atomicAdd(&lh[bp[i]>>17],1);
  __syncthreads();
  int* out = lhist + (size_t)(r*NB2+c)*RSIZE;
  for(int i=t;i<RSIZE;i+=256) out[i]=lh[i];
}

// ---------------- node-wise chunk-scan: cnt + in-place exclusive scan ------
__global__ __launch_bounds__(256) void k_sumscan(int* __restrict__ lhist, int* __restrict__ cnt){
  int n = blockIdx.x*256 + threadIdx.x;
  if(n>=NNODES) return;
  int r = n/RSIZE, i = n - r*RSIZE;
  int* base = lhist + (size_t)r*NB2*RSIZE + i;
  int run=0;
  #pragma unroll 8
  for(int c=0;c<NB2;c++){
    int v = base[(size_t)c*RSIZE];
    base[(size_t)c*RSIZE] = run;
    run += v;
  }
  cnt[n]=run;
}

// ---------------- prefix scan (row_ptr) ----------------
#define SCAN_M (NNODES+1)
#define SCAN_NB ((SCAN_M + 2047)/2048)

__global__ void k_scan_a(const int* __restrict__ cnt, int* __restrict__ bsum){
  __shared__ int red[256];
  int b=blockIdx.x, t=threadIdx.x;
  int base = b*2048 + t*8;
  int s=0;
  #pragma unroll
  for(int j=0;j<8;j++){ int idx=base+j; s += (idx<NNODES)? cnt[idx]:0; }
  red[t]=s; __syncthreads();
  for(int o=128;o>0;o>>=1){ if(t<o) red[t]+=red[t+o]; __syncthreads(); }
  if(t==0) bsum[b]=red[0];
}

__global__ void k_scan_b(int* bsum){
  if(threadIdx.x==0){
    int run=0;
    for(int i=0;i<SCAN_NB;i++){ int v=bsum[i]; bsum[i]=run; run+=v; }
  }
}

__global__ void k_scan_c(const int* __restrict__ cnt, const int* __restrict__ bsum,
                         int* __restrict__ row_ptr){
  __shared__ int lds[256];
  int b=blockIdx.x, t=threadIdx.x;
  int base=b*2048+t*8;
  int v[8]; int s=0;
  #pragma unroll
  for(int j=0;j<8;j++){ int idx=base+j; int x=(idx<NNODES)?cnt[idx]:0; v[j]=s; s+=x; }
  lds[t]=s; __syncthreads();
  for(int o=1;o<256;o<<=1){
    int other=0; if(t>=o) other=lds[t-o];
    __syncthreads();
    lds[t]+=other;
    __syncthreads();
  }
  int texcl = lds[t] - s;
  int off0 = bsum[b] + texcl;
  #pragma unroll
  for(int j=0;j<8;j++){ int idx=base+j; if(idx<SCAN_M) row_ptr[idx]=off0+v[j]; }
}

// ---------------- pass B1: LDS-offset scatter (no global atomics) ----------
__global__ __launch_bounds__(256) void k_scatter4(
    const u32* __restrict__ bkt, const int* __restrict__ gptr,
    const int* __restrict__ row_ptr, const int* __restrict__ lhist,
    int* __restrict__ col){
  __shared__ int lofs[RSIZE];
  int t=threadIdx.x;
  int r = blockIdx.x & (NRANGE-1);
  int c = blockIdx.x >> 3;
  int lo = r*RSIZE;
  const int* cb = lhist + (size_t)(r*NB2+c)*RSIZE;
  for(int i=t;i<RSIZE;i+=256) lofs[i] = row_ptr[lo+i] + cb[i];
  __syncthreads();
  int n = gptr[r];
  int per=(n+NB2-1)/NB2;
  int beg=c*per, end=beg+per; if(end>n) end=n;
  const u32* bp = bkt + (size_t)r*BCAP;
  for(int i=beg+t;i<end;i+=256){
    u32 e=bp[i];
    int pos=atomicAdd(&lofs[e>>17],1);
    col[pos]=(int)(e & 0x1FFFF);
  }
}

// ---------------- per-dst src-bin re-sort (LDS-staged) --------------------
// Block = 256 dsts; stage the block's whole col span into LDS (coalesced),
// then per-thread count/scatter from LDS. Byte-packed 8-bin counters.
__global__ __launch_bounds__(256) void k_binsort(
    const int* __restrict__ row_ptr, const int* __restrict__ col,
    int* __restrict__ col2){
  __shared__ int lcol[BSL];
  int t = threadIdx.x;
  int blk0 = blockIdx.x*256;
  int d1 = blk0+256; if(d1>NNODES) d1=NNODES;
  int s0 = row_ptr[blk0], s1 = row_ptr[d1];
  int n = s1 - s0;
  bool fit = (n<=BSL);
  if(fit){ for(int i=t;i<n;i+=256) lcol[i]=col[s0+i]; }
  __syncthreads();
  int d = blk0 + t;
  if(d<NNODES){
    int b0=row_ptr[d], b1=row_ptr[d+1];
    u64 cntp=0;
    for(int j=b0;j<b1;j++){
      int c = fit ? lcol[j-s0] : col[j];
      cntp += 1ull << ((c/RSIZE)*8);
    }
    u64 offp=0; u32 run=0;
    #pragma unroll
    for(int sb=0;sb<8;sb++){
      offp |= (u64)(run&0xffu) << (sb*8);
      run += (u32)((cntp >> (sb*8)) & 0xff);
    }
    for(int j=b0;j<b1;j++){
      int c = fit ? lcol[j-s0] : col[j];
      int sb = c/RSIZE;
      int pos = b0 + (int)((offp>>(sb*8))&0xff);
      offp += 1ull << (sb*8);
      col2[pos]=c;
    }
  }
}

// ---------------- MFMA GEMM + fused BN/ELU + alpha epilogue ----------------
template<int K, int OUTC, int HID, bool XEXT, bool BN>
__global__ __launch_bounds__(256) void k_gemm_mfma(
    const void* __restrict__ xin, const void* __restrict__ W,
    const void* __restrict__ avs, const void* __restrict__ avd,
    const float2* __restrict__ bnab,
    u16* __restrict__ hout, float* __restrict__ asrc, float* __restrict__ adst,
    const int* __restrict__ flagp)
{
  const int f = flagp[0];
  constexpr int KP = K+8;          // WT row stride (u16), 16B-aligned rows
  constexpr int RS = OUTC+8;       // HROW row stride (u16)
  constexpr int NT = OUTC/16;      // col tiles per wave
  constexpr int KQ = K/32;         // mfma K steps
  __shared__ __align__(16) u16 WT[OUTC*KP];
  __shared__ __align__(16) u16 HROW[4*16*RS];
  __shared__ float AVb[2*OUTC];
  __shared__ float2 BB[K];
  int t=threadIdx.x;
  const u16* Wu=(const u16*)W; const float* Wf=(const float*)W;
  for(int i8=t*8; i8<K*OUTC; i8+=256*8){
    int k=i8/OUTC, c0=i8-k*OUTC;     // OUTC divisible by 8 -> row-local
    u16 w8[8];
    if(f){
      const float* wp=Wf+i8;
      float4 a=*(const float4*)wp, b=*(const float4*)(wp+4);
      w8[0]=f2b(a.x);w8[1]=f2b(a.y);w8[2]=f2b(a.z);w8[3]=f2b(a.w);
      w8[4]=f2b(b.x);w8[5]=f2b(b.y);w8[6]=f2b(b.z);w8[7]=f2b(b.w);
    } else {
      uint4 q=*(const uint4*)(Wu+i8);
      w8[0]=q.x&0xffff;w8[1]=q.x>>16;w8[2]=q.y&0xffff;w8[3]=q.y>>16;
      w8[4]=q.z&0xffff;w8[5]=q.z>>16;w8[6]=q.w&0xffff;w8[7]=q.w>>16;
    }
    #pragma unroll
    for(int u=0;u<8;u++) WT[(c0+u)*KP + k] = w8[u];
  }
  for(int idx=t; idx<2*OUTC; idx+=256)
    AVb[idx] = (idx<OUTC)? ldf(avs,idx,f) : ldf(avd,idx-OUTC,f);
  if(BN) for(int idx=t; idx<K; idx+=256) BB[idx]=bnab[idx];
  __syncthreads();

  int wv=t>>6, lane=t&63;
  int m=lane&15, quad=lane>>4;
  int grow0 = blockIdx.x*64 + wv*16;
  int growA = grow0 + m;
  bool avalid = growA < NNODES;
  int growC = avalid ? growA : 0;

  f32x4 acc[NT] = {};
  #pragma unroll
  for(int kq=0;kq<KQ;kq++){
    int k0 = kq*32 + quad*8;
    union{ u32 u[4]; short8 s8; } A;
    if(XEXT && f==1){
      const float* xr=(const float*)xin + (size_t)growC*K + k0;
      float4 p=*(const float4*)xr, q=*(const float4*)(xr+4);
      A.u[0]=f2b(p.x)|((u32)f2b(p.y)<<16);
      A.u[1]=f2b(p.z)|((u32)f2b(p.w)<<16);
      A.u[2]=f2b(q.x)|((u32)f2b(q.y)<<16);
      A.u[3]=f2b(q.z)|((u32)f2b(q.w)<<16);
    } else {
      uint4 q=*(const uint4*)((const u16*)xin + (size_t)growC*K + k0);
      A.u[0]=q.x; A.u[1]=q.y; A.u[2]=q.z; A.u[3]=q.w;
    }
    if(BN){
      #pragma unroll
      for(int j=0;j<4;j++){
        float lo=b2f(A.u[j]&0xffff), hi=b2f(A.u[j]>>16);
        float2 c1=BB[k0+2*j], c2=BB[k0+2*j+1];
        lo=c1.x*lo+c1.y; lo = lo>0.f? lo : __expf(lo)-1.f;
        hi=c2.x*hi+c2.y; hi = hi>0.f? hi : __expf(hi)-1.f;
        A.u[j]=f2b(lo)|((u32)f2b(hi)<<16);
      }
    }
    #pragma unroll
    for(int nt=0;nt<NT;nt++){
      union{ uint4 q; short8 s8; } Bf;
      Bf.q = *(const uint4*)&WT[(nt*16+m)*KP + k0];
      acc[nt] = __builtin_amdgcn_mfma_f32_16x16x32_bf16(A.s8, Bf.s8, acc[nt], 0,0,0);
    }
  }
  u16* hr = &HROW[wv*16*RS];
  #pragma unroll
  for(int nt=0;nt<NT;nt++){
    #pragma unroll
    for(int reg=0;reg<4;reg++)
      hr[(quad*4+reg)*RS + nt*16+m] = f2b(acc[nt][reg]);
  }
  __syncthreads();
  {
    int row=lane&15, task=quad, head=task&1, sd=task>>1;
    float p=0.f;
    const u16* hrow=&hr[row*RS + head*HID];
    const float* av=&AVb[sd*OUTC + head*HID];
    #pragma unroll 8
    for(int c=0;c<HID;c++) p += b2f(hrow[c])*av[c];
    int grow=grow0+row;
    if(grow<NNODES){ (sd? adst:asrc)[grow*2+head]=p; }
  }
  {
    constexpr int CH8 = OUTC/8;
    for(int idx=lane; idx<16*CH8; idx+=64){
      int rr=idx/CH8, c8=idx-rr*CH8;
      int grow=grow0+rr;
      if(grow<NNODES)
        *(uint4*)(hout + (size_t)grow*OUTC + c8*8) = *(const uint4*)&hr[rr*RS + c8*8];
    }
  }
}

// ---------------- fused softmax + gather-aggregate (balanced phases) -------
// 8 dsts per wave: group g = tid>>3 (32 dsts/block), lane cg = tid&7 owns
// channels [cg*8, cg*8+8). Edge lists src-bin-ordered (k_binsort); 4 balanced
// phases (equal quarters of each dst's list) with block barriers: same work
// per group per phase, segments track ~3.2MB L2-resident src windows.
// Non-final: single exp per lane (own head only, own-sum normalize).
// XCD-swizzled (blockIdx%8).
template<int OUTC, bool FINAL>
__global__ __launch_bounds__(256) void k_aggf(
  const int* __restrict__ row_ptr, const int* __restrict__ col2,
  const u16* __restrict__ hin, const float* __restrict__ asrcf,
  const float2* __restrict__ adst2, const void* __restrict__ bias,
  u16* __restrict__ houtb, void* __restrict__ outv, const int* __restrict__ flagp)
{
  const int f = flagp[0];
  __shared__ float vbuf[FINAL?32:1][84];
  int t = threadIdx.x;
  int g  = t>>3;            // dst group within block, 0..31
  int cg = t&7;             // channel group
  int rr = blockIdx.x & 7, jb = blockIdx.x >> 3;
  int lim = RSIZE - jb*32;              // valid groups in this block
  bool ok = g < lim;
  int d = rr*RSIZE + jb*32 + g;
  int base=0, deg=0;
  float2 adv = make_float2(0.f,0.f);
  if(ok){
    base = row_ptr[d];
    deg  = row_ptr[d+1] - base;
    adv  = adst2[d];
  }
  const int* cp  = col2 + base;
  const u16* hcg = hin + cg*8;          // per-lane channel base
  float acc[8]={0,0,0,0,0,0,0,0};

  if(!FINAL){
    // ---- single-exp path: lane only needs its own head ----
    int ho = (cg>=4)?1:0;
    float aown = ho ? adv.y : adv.x;
    float s=0.f;
    for(int ph=0; ph<4; ++ph){
      int beg = (deg*ph)>>2;
      int end = (deg*(ph+1))>>2;
      for(int j=beg; j<end; j+=2){
        int c0 = cp[j];
        bool v1 = (j+1)<end;
        int c1 = cp[v1 ? j+1 : j];
        float sa = asrcf[c0*2+ho];
        float sb = asrcf[c1*2+ho];
        uint4 h0 = *(const uint4*)(hcg + (size_t)c0*OUTC);
        uint4 h1 = *(const uint4*)(hcg + (size_t)c1*OUTC);
        float e0 = sa+aown; e0 = fmaxf(e0, NEG_SLOPE*e0); e0 = fminf(e0,60.f);
        float e1 = sb+aown; e1 = fmaxf(e1, NEG_SLOPE*e1); e1 = fminf(e1,60.f);
        float p0 = __expf(e0), p1 = __expf(e1);
        if(!v1) p1 = 0.f;
        s += p0 + p1;
        acc[0] += p0*blo(h0.x) + p1*blo(h1.x);
        acc[1] += p0*bhi(h0.x) + p1*bhi(h1.x);
        acc[2] += p0*blo(h0.y) + p1*blo(h1.y);
        acc[3] += p0*bhi(h0.y) + p1*bhi(h1.y);
        acc[4] += p0*blo(h0.z) + p1*blo(h1.z);
        acc[5] += p0*bhi(h0.z) + p1*bhi(h1.z);
        acc[6] += p0*blo(h0.w) + p1*blo(h1.w);
        acc[7] += p0*bhi(h0.w) + p1*bhi(h1.w);
      }
      __syncthreads();   // phase barrier: keep block inside one src window
    }
    float inv = s>0.f ? 1.f/s : 0.f;
    if(ok){
      u16 o8[8];
      #pragma unroll
      for(int k=0;k<8;k++) o8[k]=f2b(acc[k]*inv + ldf(bias,cg*8+k,f));
      uint4 ov;
      ov.x=(u32)o8[0]|((u32)o8[1]<<16); ov.y=(u32)o8[2]|((u32)o8[3]<<16);
      ov.z=(u32)o8[4]|((u32)o8[5]<<16); ov.w=(u32)o8[6]|((u32)o8[7]<<16);
      *(uint4*)(houtb + (size_t)d*64 + cg*8) = ov;
    }
  } else {
    // ---- final layer: dual exp (cross-head accx), head mean via vbuf ----
    const float2* asrc2 = (const float2*)asrcf;
    const u16* hxg = hin + 64 + cg*2;
    float accx0=0.f, accx1=0.f;
    float s0=0.f, s1=0.f;
    for(int ph=0; ph<4; ++ph){
      int beg = (deg*ph)>>2;
      int end = (deg*(ph+1))>>2;
      for(int j=beg; j<end; j+=2){
        int c0 = cp[j];
        bool v1 = (j+1)<end;
        int c1 = cp[v1 ? j+1 : j];
        float2 sa = asrc2[c0];
        float2 sv = asrc2[c1];
        const u16* hp0 = hcg + (size_t)c0*OUTC;
        const u16* hp1 = hcg + (size_t)c1*OUTC;
        uint4 h0 = *(const uint4*)hp0;
        uint4 h1 = *(const uint4*)hp1;
        float e0 = sa.x+adv.x; e0 = fmaxf(e0, NEG_SLOPE*e0); e0 = fminf(e0,60.f);
        float e1 = sa.y+adv.y; e1 = fmaxf(e1, NEG_SLOPE*e1); e1 = fminf(e1,60.f);
        float p0 = __expf(e0), p1 = __expf(e1);
        float q0 = sv.x+adv.x; q0 = fmaxf(q0, NEG_SLOPE*q0); q0 = fminf(q0,60.f);
        float q1 = sv.y+adv.y; q1 = fmaxf(q1, NEG_SLOPE*q1); q1 = fminf(q1,60.f);
        float r0 = __expf(q0), r1 = __expf(q1);
        if(!v1){ r0=0.f; r1=0.f; }
        s0 += p0 + r0; s1 += p1 + r1;
        float pa = (cg<5)? p0 : p1;
        float pb = (cg<5)? r0 : r1;
        acc[0] += pa*blo(h0.x) + pb*blo(h1.x);
        acc[1] += pa*bhi(h0.x) + pb*bhi(h1.x);
        acc[2] += pa*blo(h0.y) + pb*blo(h1.y);
        acc[3] += pa*bhi(h0.y) + pb*bhi(h1.y);
        acc[4] += pa*blo(h0.z) + pb*blo(h1.z);
        acc[5] += pa*bhi(h0.z) + pb*bhi(h1.z);
        acc[6] += pa*blo(h0.w) + pb*blo(h1.w);
        acc[7] += pa*bhi(h0.w) + pb*bhi(h1.w);
        ushort2 ha = *(const ushort2*)(hxg + (size_t)c0*OUTC);
        ushort2 hb = *(const ushort2*)(hxg + (size_t)c1*OUTC);
        accx0 += p1*b2f(ha.x) + r1*b2f(hb.x);
        accx1 += p1*b2f(ha.y) + r1*b2f(hb.y);
      }
      __syncthreads();   // phase barrier
    }
    float inv0 = s0>0.f?1.f/s0:0.f, inv1 = s1>0.f?1.f/s1:0.f;
    if(ok){
      #pragma unroll
      for(int k=0;k<8;k++)
        vbuf[g][cg*8+k] = acc[k]*((cg<5)?inv0:inv1);
      vbuf[g][64+cg*2]   = accx0*inv1;
      vbuf[g][64+cg*2+1] = accx1*inv1;
    }
    __syncthreads();
    for(int idx=t; idx<32*40; idx+=256){
      int gg=idx/40, ch=idx-gg*40;
      if(gg<lim){
        int dd = rr*RSIZE + jb*32 + gg;
        float res = 0.5f*(vbuf[gg][ch] + vbuf[gg][40+ch]) + ldf(bias,ch,f);
        if(f) ((float*)outv)[(size_t)dd*40+ch] = res;
        else  ((__hip_bfloat16*)outv)[(size_t)dd*40+ch] = __float2bfloat16(res);
      }
    }
  }
}

// ---------------- batch norm (stats + coefficient finalize) ---------------
__global__ __launch_bounds__(256) void k_bnstats(const u16* __restrict__ h, float* __restrict__ stats){
  __shared__ float red[4][128];
  int t=threadIdx.x; int c=t&63; int g=t>>6;
  float s=0.f,q=0.f;
  for(int r=blockIdx.x*4+g; r<NNODES; r+=gridDim.x*4){
    float v=b2f(h[(size_t)r*64+c]); s+=v; q+=v*v;
  }
  red[g][c]=s; red[g][64+c]=q;
  __syncthreads();
  if(t<128){
    float tot=red[0][t]+red[1][t]+red[2][t]+red[3][t];
    atomicAdd(&stats[t], tot);
  }
}

__global__ void k_bnfinal(const float* __restrict__ stats,
                          const void* __restrict__ gm, const void* __restrict__ bt,
                          float2* __restrict__ bnab, const int* __restrict__ flagp){
  const int f = flagp[0];
  int c=threadIdx.x;
  if(c>=64) return;
  float mu=stats[c]*(1.0f/NNODES);
  float var=stats[64+c]*(1.0f/NNODES)-mu*mu;
  var = var>0.f?var:0.f;
  float A = ldf(gm,c,f)*rsqrtf(var+BN_EPS);
  float B = ldf(bt,c,f) - A*mu;
  bnab[c]=make_float2(A,B);
}

extern "C" void kernel_launch(void* const* d_in, const int* in_sizes, int n_in,
                              void* d_out, int out_size, void* d_ws, size_t ws_size,
                              hipStream_t stream){
  const void* x  =d_in[0];
  const int* ei =(const int*)d_in[1];
  const void* W0 =d_in[2];  const void* as0=d_in[3];  const void* ad0=d_in[4];
  const void* b0 =d_in[5];  const void* g0 =d_in[6];  const void* bt0=d_in[7];
  const void* W1 =d_in[8];  const void* as1=d_in[9];  const void* ad1=d_in[10];
  const void* b1 =d_in[11]; const void* g1 =d_in[12]; const void* bt1=d_in[13];
  const void* W2 =d_in[14]; const void* as2=d_in[15]; const void* ad2=d_in[16];
  const void* b2 =d_in[17];

  char* ws=(char*)d_ws;
  size_t off=0;
  auto alloc=[&](size_t bytes)->void*{ void* p=ws+off; off+=(bytes+255)&~(size_t)255; return p; };
  int*    flag   =(int*)   alloc(256);
  int*    row_ptr=(int*)   alloc((size_t)(NNODES+1)*4);
  int*    cnt    =(int*)   alloc((size_t)NNODES*4);
  int*    colx   =(int*)   alloc((size_t)ENTOT*4);
  int*    colx2  =(int*)   alloc((size_t)ENTOT*4);
  int*    bsum   =(int*)   alloc((size_t)SCAN_NB*4);
  int*    gptr   =(int*)   alloc(256);
  u32*    bkt    =(u32*)   alloc((size_t)NRANGE*BCAP*4);
  u16*    hA     =(u16*)   alloc((size_t)100032*80*2);   // aliased as lhist during CSR build
  u16*    hB0    =(u16*)   alloc((size_t)100032*64*2);
  u16*    hB1    =(u16*)   alloc((size_t)100032*64*2);
  float*  asrc   =(float*) alloc((size_t)NNODES*2*4);
  float*  adst   =(float*) alloc((size_t)NNODES*2*4);
  float*  stats  =(float*) alloc(128*4);
  float2* bnab   =(float2*)alloc(64*8);
  int*    lhist  =(int*)hA;   // 12.8 MB needed, hA is 16 MB; dead before gemm L0

  k_detect<<<1,256,0,stream>>>((const u16*)x, flag);

  // CSR: partition -> LDS hist -> chunk scan -> row_ptr scan -> LDS scatter
  (void)hipMemsetAsync(gptr,0,256,stream);
  k_part2  <<<PBLK,256,0,stream>>>(ei,gptr,bkt);
  k_hist4  <<<NRANGE*NB2,256,0,stream>>>(bkt,gptr,lhist);
  k_sumscan<<<(NNODES+255)/256,256,0,stream>>>(lhist,cnt);
  k_scan_a <<<SCAN_NB,256,0,stream>>>(cnt,bsum);
  k_scan_b <<<1,64,0,stream>>>(bsum);
  k_scan_c <<<SCAN_NB,256,0,stream>>>(cnt,bsum,row_ptr);
  k_scatter4<<<NRANGE*NB2,256,0,stream>>>(bkt,gptr,row_ptr,lhist,colx);
  k_binsort<<<(NNODES+255)/256,256,0,stream>>>(row_ptr,colx,colx2);

  int gG = (NNODES+63)/64;                 // 1563
  int gA = NRANGE * ((RSIZE + 31)/32);     // 8 x 391 = 3128 (32 dsts/block)
  // ---- layer 0 ----
  k_gemm_mfma<128,64,32,true ,false><<<gG,256,0,stream>>>(
      x,W0,as0,ad0,nullptr,hA,asrc,adst,flag);
  k_aggf<64,false><<<gA,256,0,stream>>>(row_ptr,colx2,hA,
      asrc,(const float2*)adst,b0,hB0,nullptr,flag);
  (void)hipMemsetAsync(stats,0,512,stream);
  k_bnstats<<<256,256,0,stream>>>(hB0,stats);
  k_bnfinal<<<1,64,0,stream>>>(stats,g0,bt0,bnab,flag);
  // ---- layer 1 ----
  k_gemm_mfma<64,64,32,false,true ><<<gG,256,0,stream>>>(
      hB0,W1,as1,ad1,bnab,hA,asrc,adst,flag);
  k_aggf<64,false><<<gA,256,0,stream>>>(row_ptr,colx2,hA,
      asrc,(const float2*)adst,b1,hB1,nullptr,flag);
  (void)hipMemsetAsync(stats,0,512,stream);
  k_bnstats<<<256,256,0,stream>>>(hB1,stats);
  k_bnfinal<<<1,64,0,stream>>>(stats,g1,bt1,bnab,flag);
  // ---- layer 2 (head mean -> d_out) ----
  k_gemm_mfma<64,80,40,false,true ><<<gG,256,0,stream>>>(
      hB1,W2,as2,ad2,bnab,hA,asrc,adst,flag);
  k_aggf<80,true ><<<gA,256,0,stream>>>(row_ptr,colx2,hA,
      asrc,(const float2*)adst,b2,nullptr,d_out,flag);

  (void)in_sizes;(void)n_in;(void)out_size;(void)ws_size;
}

// Round 8
// 462.046 us; speedup vs baseline: 1.4788x; 1.0088x over previous
//
#include <hip/hip_runtime.h>
#include <hip/hip_bf16.h>
#include <math.h>

// GAT: N=100000 nodes, E=1600000 edges (+N self loops), 3 layers.
// Inputs bf16 (runtime-detected flag kept). Intermediates bf16.
// CSR build: atomic-free counting sort (8 dst-range buckets) + per-dst
// src-bin re-sort (k_binsort: LDS-staged reads AND LDS-scattered writes ->
// coalesced col2 stores, no write-allocate blowup). Aggregation: 8 dsts per
// wave (8 lanes/dst, 8ch/lane), 4 BALANCED phases (equal quarters of each
// dst's bin-sorted list -> ~3.2MB L2-resident src windows). Non-final
// layers: single-exp per lane (own head only). XCD-swizzled.

#define NNODES 100000
#define NEDGES 1600000
#define ENTOT  (NEDGES + NNODES)
#define NEG_SLOPE 0.2f
#define BN_EPS 1e-5f

#define NRANGE 8
#define RSIZE  (NNODES/NRANGE)     // 12500 (also src-bin size)
#define BCAP   262144              // per-bucket capacity (mean 212.5k)
#define PBLK   2048                // partition blocks
#define NB2    32                  // chunks per range
#define BSL    6144                // binsort LDS staging (ints; span~4350±64)

typedef unsigned short u16;
typedef unsigned int u32;
typedef unsigned long long u64;
typedef __attribute__((ext_vector_type(8))) short short8;
typedef __attribute__((ext_vector_type(4))) float f32x4;

__device__ __forceinline__ float b2f(u16 u){ union{u32 i; float f;} v; v.i=((u32)u)<<16; return v.f; }
__device__ __forceinline__ float blo(u32 u){ union{u32 i; float f;} v; v.i=u<<16; return v.f; }
__device__ __forceinline__ float bhi(u32 u){ union{u32 i; float f;} v; v.i=u&0xffff0000u; return v.f; }
__device__ __forceinline__ u16 f2b(float x){ __hip_bfloat16 b=__float2bfloat16(x); return *(u16*)&b; }
__device__ __forceinline__ float ldf(const void* p, int i, int f){
  return f ? ((const float*)p)[i] : b2f(((const u16*)p)[i]);
}

// ---------------- dtype probe ----------------
__global__ void k_detect(const u16* __restrict__ x, int* __restrict__ flag){
  __shared__ int bad;
  if(threadIdx.x==0) bad=0;
  __syncthreads();
  int cnt=0;
  for(int i=threadIdx.x;i<4096;i+=256){
    u16 v = x[2*i];
    int ex = (v>>7)&0xff;
    if(ex==0xff || (ex==0 && (v&0x7fff)!=0)) cnt++;
  }
  atomicAdd(&bad,cnt);
  __syncthreads();
  if(threadIdx.x==0) flag[0] = (bad>4)?1:0;   // 1 = fp32, 0 = bf16
}

// ---------------- pass A: partition edges into 8 dst-range buckets ---------
__global__ __launch_bounds__(256) void k_part2(
    const int* __restrict__ ei, int* __restrict__ gptr, u32* __restrict__ bkt){
  __shared__ int lcnt[NRANGE], gbase[NRANGE];
  int t=threadIdx.x;
  if(t<NRANGE) lcnt[t]=0;
  __syncthreads();
  const int CH=(ENTOT+PBLK-1)/PBLK;   // 831
  int beg=blockIdx.x*CH, end=beg+CH; if(end>ENTOT) end=ENTOT;
  int nd[4], ns[4], nr[4], ne=0;
  for(int i=beg+t; i<end; i+=256){
    int d=(i<NEDGES)? ei[NEDGES+i] : (i-NEDGES);
    int s=(i<NEDGES)? ei[i] : d;
    nd[ne]=d; ns[ne]=s; ne++;
  }
  #pragma unroll 4
  for(int k=0;k<ne;k++) nr[k]=atomicAdd(&lcnt[nd[k]/RSIZE],1);
  __syncthreads();
  if(t<NRANGE) gbase[t]=atomicAdd(&gptr[t],lcnt[t]);
  __syncthreads();
  #pragma unroll 4
  for(int k=0;k<ne;k++){
    int r=nd[k]/RSIZE;
    u32 e = ((u32)(nd[k]-r*RSIZE)<<17) | (u32)ns[k];   // dst_local(14b)|src(17b)
    __builtin_nontemporal_store(e, &bkt[(size_t)r*BCAP + gbase[r] + nr[k]]);
  }
}

// ---------------- pass B0: per-(range,chunk) LDS histogram -----------------
__global__ __launch_bounds__(256) void k_hist4(
    const u32* __restrict__ bkt, const int* __restrict__ gptr, int* __restrict__ lhist){
  __shared__ int lh[RSIZE];
  int t=threadIdx.x;
  for(int i=t;i<RSIZE;i+=256) lh[i]=0;
  __syncthreads();
  int r = blockIdx.x & (NRANGE-1);
  int c = blockIdx.x >> 3;
  int n = gptr[r];
  int per=(n+NB2-1)/NB2;
  int beg=c*per, end=beg+per; if(end>n) end=n;
  const u32* bp = bkt + (size_t)r*BCAP;
  for(int i=beg+t;i<end;i+=256) atomicAdd(&lh[bp[i]>>17],1);
  __syncthreads();
  int* out = lhist + (size_t)(r*NB2+c)*RSIZE;
  for(int i=t;i<RSIZE;i+=256) out[i]=lh[i];
}

// ---------------- node-wise chunk-scan: cnt + in-place exclusive scan ------
__global__ __launch_bounds__(256) void k_sumscan(int* __restrict__ lhist, int* __restrict__ cnt){
  int n = blockIdx.x*256 + threadIdx.x;
  if(n>=NNODES) return;
  int r = n/RSIZE, i = n - r*RSIZE;
  int* base = lhist + (size_t)r*NB2*RSIZE + i;
  int run=0;
  #pragma unroll 8
  for(int c=0;c<NB2;c++){
    int v = base[(size_t)c*RSIZE];
    base[(size_t)c*RSIZE] = run;
    run += v;
  }
  cnt[n]=run;
}

// ---------------- prefix scan (row_ptr) ----------------
#define SCAN_M (NNODES+1)
#define SCAN_NB ((SCAN_M + 2047)/2048)

__global__ void k_scan_a(const int* __restrict__ cnt, int* __restrict__ bsum){
  __shared__ int red[256];
  int b=blockIdx.x, t=threadIdx.x;
  int base = b*2048 + t*8;
  int s=0;
  #pragma unroll
  for(int j=0;j<8;j++){ int idx=base+j; s += (idx<NNODES)? cnt[idx]:0; }
  red[t]=s; __syncthreads();
  for(int o=128;o>0;o>>=1){ if(t<o) red[t]+=red[t+o]; __syncthreads(); }
  if(t==0) bsum[b]=red[0];
}

__global__ void k_scan_b(int* bsum){
  if(threadIdx.x==0){
    int run=0;
    for(int i=0;i<SCAN_NB;i++){ int v=bsum[i]; bsum[i]=run; run+=v; }
  }
}

__global__ void k_scan_c(const int* __restrict__ cnt, const int* __restrict__ bsum,
                         int* __restrict__ row_ptr){
  __shared__ int lds[256];
  int b=blockIdx.x, t=threadIdx.x;
  int base=b*2048+t*8;
  int v[8]; int s=0;
  #pragma unroll
  for(int j=0;j<8;j++){ int idx=base+j; int x=(idx<NNODES)?cnt[idx]:0; v[j]=s; s+=x; }
  lds[t]=s; __syncthreads();
  for(int o=1;o<256;o<<=1){
    int other=0; if(t>=o) other=lds[t-o];
    __syncthreads();
    lds[t]+=other;
    __syncthreads();
  }
  int texcl = lds[t] - s;
  int off0 = bsum[b] + texcl;
  #pragma unroll
  for(int j=0;j<8;j++){ int idx=base+j; if(idx<SCAN_M) row_ptr[idx]=off0+v[j]; }
}

// ---------------- pass B1: LDS-offset scatter (no global atomics) ----------
__global__ __launch_bounds__(256) void k_scatter4(
    const u32* __restrict__ bkt, const int* __restrict__ gptr,
    const int* __restrict__ row_ptr, const int* __restrict__ lhist,
    int* __restrict__ col){
  __shared__ int lofs[RSIZE];
  int t=threadIdx.x;
  int r = blockIdx.x & (NRANGE-1);
  int c = blockIdx.x >> 3;
  int lo = r*RSIZE;
  const int* cb = lhist + (size_t)(r*NB2+c)*RSIZE;
  for(int i=t;i<RSIZE;i+=256) lofs[i] = row_ptr[lo+i] + cb[i];
  __syncthreads();
  int n = gptr[r];
  int per=(n+NB2-1)/NB2;
  int beg=c*per, end=beg+per; if(end>n) end=n;
  const u32* bp = bkt + (size_t)r*BCAP;
  for(int i=beg+t;i<end;i+=256){
    u32 e=bp[i];
    int pos=atomicAdd(&lofs[e>>17],1);
    col[pos]=(int)(e & 0x1FFFF);
  }
}

// ---------------- per-dst src-bin re-sort (LDS in, LDS out) ---------------
// Block = 256 dsts; stage the block's whole col span into LDS (coalesced),
// per-thread count/scatter INTO LDS (no global write-allocate blowup),
// then coalesced copy LDS -> col2. Byte-packed 8-bin counters.
__global__ __launch_bounds__(256) void k_binsort(
    const int* __restrict__ row_ptr, const int* __restrict__ col,
    int* __restrict__ col2){
  __shared__ int lcol[BSL];
  __shared__ int lout[BSL];
  int t = threadIdx.x;
  int blk0 = blockIdx.x*256;
  int d1 = blk0+256; if(d1>NNODES) d1=NNODES;
  int s0 = row_ptr[blk0], s1 = row_ptr[d1];
  int n = s1 - s0;
  bool fit = (n<=BSL);
  if(fit){ for(int i=t;i<n;i+=256) lcol[i]=col[s0+i]; }
  __syncthreads();
  int d = blk0 + t;
  if(d<NNODES){
    int b0=row_ptr[d], b1=row_ptr[d+1];
    u64 cntp=0;
    for(int j=b0;j<b1;j++){
      int c = fit ? lcol[j-s0] : col[j];
      cntp += 1ull << ((c/RSIZE)*8);
    }
    u64 offp=0; u32 run=0;
    #pragma unroll
    for(int sb=0;sb<8;sb++){
      offp |= (u64)(run&0xffu) << (sb*8);
      run += (u32)((cntp >> (sb*8)) & 0xff);
    }
    for(int j=b0;j<b1;j++){
      int c = fit ? lcol[j-s0] : col[j];
      int sb = c/RSIZE;
      int pos = (b0-s0) + (int)((offp>>(sb*8))&0xff);
      offp += 1ull << (sb*8);
      if(fit) lout[pos]=c; else col2[s0+pos]=c;
    }
  }
  __syncthreads();
  if(fit){ for(int i=t;i<n;i+=256) col2[s0+i]=lout[i]; }
}

// ---------------- MFMA GEMM + fused BN/ELU + alpha epilogue ----------------
template<int K, int OUTC, int HID, bool XEXT, bool BN>
__global__ __launch_bounds__(256) void k_gemm_mfma(
    const void* __restrict__ xin, const void* __restrict__ W,
    const void* __restrict__ avs, const void* __restrict__ avd,
    const float2* __restrict__ bnab,
    u16* __restrict__ hout, float* __restrict__ asrc, float* __restrict__ adst,
    const int* __restrict__ flagp)
{
  const int f = flagp[0];
  constexpr int KP = K+8;          // WT row stride (u16), 16B-aligned rows
  constexpr int RS = OUTC+8;       // HROW row stride (u16)
  constexpr int NT = OUTC/16;      // col tiles per wave
  constexpr int KQ = K/32;         // mfma K steps
  __shared__ __align__(16) u16 WT[OUTC*KP];
  __shared__ __align__(16) u16 HROW[4*16*RS];
  __shared__ float AVb[2*OUTC];
  __shared__ float2 BB[K];
  int t=threadIdx.x;
  const u16* Wu=(const u16*)W; const float* Wf=(const float*)W;
  for(int i8=t*8; i8<K*OUTC; i8+=256*8){
    int k=i8/OUTC, c0=i8-k*OUTC;     // OUTC divisible by 8 -> row-local
    u16 w8[8];
    if(f){
      const float* wp=Wf+i8;
      float4 a=*(const float4*)wp, b=*(const float4*)(wp+4);
      w8[0]=f2b(a.x);w8[1]=f2b(a.y);w8[2]=f2b(a.z);w8[3]=f2b(a.w);
      w8[4]=f2b(b.x);w8[5]=f2b(b.y);w8[6]=f2b(b.z);w8[7]=f2b(b.w);
    } else {
      uint4 q=*(const uint4*)(Wu+i8);
      w8[0]=q.x&0xffff;w8[1]=q.x>>16;w8[2]=q.y&0xffff;w8[3]=q.y>>16;
      w8[4]=q.z&0xffff;w8[5]=q.z>>16;w8[6]=q.w&0xffff;w8[7]=q.w>>16;
    }
    #pragma unroll
    for(int u=0;u<8;u++) WT[(c0+u)*KP + k] = w8[u];
  }
  for(int idx=t; idx<2*OUTC; idx+=256)
    AVb[idx] = (idx<OUTC)? ldf(avs,idx,f) : ldf(avd,idx-OUTC,f);
  if(BN) for(int idx=t; idx<K; idx+=256) BB[idx]=bnab[idx];
  __syncthreads();

  int wv=t>>6, lane=t&63;
  int m=lane&15, quad=lane>>4;
  int grow0 = blockIdx.x*64 + wv*16;
  int growA = grow0 + m;
  bool avalid = growA < NNODES;
  int growC = avalid ? growA : 0;

  f32x4 acc[NT] = {};
  #pragma unroll
  for(int kq=0;kq<KQ;kq++){
    int k0 = kq*32 + quad*8;
    union{ u32 u[4]; short8 s8; } A;
    if(XEXT && f==1){
      const float* xr=(const float*)xin + (size_t)growC*K + k0;
      float4 p=*(const float4*)xr, q=*(const float4*)(xr+4);
      A.u[0]=f2b(p.x)|((u32)f2b(p.y)<<16);
      A.u[1]=f2b(p.z)|((u32)f2b(p.w)<<16);
      A.u[2]=f2b(q.x)|((u32)f2b(q.y)<<16);
      A.u[3]=f2b(q.z)|((u32)f2b(q.w)<<16);
    } else {
      uint4 q=*(const uint4*)((const u16*)xin + (size_t)growC*K + k0);
      A.u[0]=q.x; A.u[1]=q.y; A.u[2]=q.z; A.u[3]=q.w;
    }
    if(BN){
      #pragma unroll
      for(int j=0;j<4;j++){
        float lo=b2f(A.u[j]&0xffff), hi=b2f(A.u[j]>>16);
        float2 c1=BB[k0+2*j], c2=BB[k0+2*j+1];
        lo=c1.x*lo+c1.y; lo = lo>0.f? lo : __expf(lo)-1.f;
        hi=c2.x*hi+c2.y; hi = hi>0.f? hi : __expf(hi)-1.f;
        A.u[j]=f2b(lo)|((u32)f2b(hi)<<16);
      }
    }
    #pragma unroll
    for(int nt=0;nt<NT;nt++){
      union{ uint4 q; short8 s8; } Bf;
      Bf.q = *(const uint4*)&WT[(nt*16+m)*KP + k0];
      acc[nt] = __builtin_amdgcn_mfma_f32_16x16x32_bf16(A.s8, Bf.s8, acc[nt], 0,0,0);
    }
  }
  u16* hr = &HROW[wv*16*RS];
  #pragma unroll
  for(int nt=0;nt<NT;nt++){
    #pragma unroll
    for(int reg=0;reg<4;reg++)
      hr[(quad*4+reg)*RS + nt*16+m] = f2b(acc[nt][reg]);
  }
  __syncthreads();
  {
    int row=lane&15, task=quad, head=task&1, sd=task>>1;
    float p=0.f;
    const u16* hrow=&hr[row*RS + head*HID];
    const float* av=&AVb[sd*OUTC + head*HID];
    #pragma unroll 8
    for(int c=0;c<HID;c++) p += b2f(hrow[c])*av[c];
    int grow=grow0+row;
    if(grow<NNODES){ (sd? adst:asrc)[grow*2+head]=p; }
  }
  {
    constexpr int CH8 = OUTC/8;
    for(int idx=lane; idx<16*CH8; idx+=64){
      int rr=idx/CH8, c8=idx-rr*CH8;
      int grow=grow0+rr;
      if(grow<NNODES)
        *(uint4*)(hout + (size_t)grow*OUTC + c8*8) = *(const uint4*)&hr[rr*RS + c8*8];
    }
  }
}

// ---------------- fused softmax + gather-aggregate (balanced phases) -------
// 8 dsts per wave: group g = tid>>3 (32 dsts/block), lane cg = tid&7 owns
// channels [cg*8, cg*8+8). Edge lists src-bin-ordered (k_binsort); 4 balanced
// phases (equal quarters of each dst's list) with block barriers: same work
// per group per phase, segments track ~3.2MB L2-resident src windows.
// Non-final: single exp per lane (own head only, own-sum normalize).
// XCD-swizzled (blockIdx%8).
template<int OUTC, bool FINAL>
__global__ __launch_bounds__(256) void k_aggf(
  const int* __restrict__ row_ptr, const int* __restrict__ col2,
  const u16* __restrict__ hin, const float* __restrict__ asrcf,
  const float2* __restrict__ adst2, const void* __restrict__ bias,
  u16* __restrict__ houtb, void* __restrict__ outv, const int* __restrict__ flagp)
{
  const int f = flagp[0];
  __shared__ float vbuf[FINAL?32:1][84];
  int t = threadIdx.x;
  int g  = t>>3;            // dst group within block, 0..31
  int cg = t&7;             // channel group
  int rr = blockIdx.x & 7, jb = blockIdx.x >> 3;
  int lim = RSIZE - jb*32;              // valid groups in this block
  bool ok = g < lim;
  int d = rr*RSIZE + jb*32 + g;
  int base=0, deg=0;
  float2 adv = make_float2(0.f,0.f);
  if(ok){
    base = row_ptr[d];
    deg  = row_ptr[d+1] - base;
    adv  = adst2[d];
  }
  const int* cp  = col2 + base;
  const u16* hcg = hin + cg*8;          // per-lane channel base
  float acc[8]={0,0,0,0,0,0,0,0};

  if(!FINAL){
    // ---- single-exp path: lane only needs its own head ----
    int ho = (cg>=4)?1:0;
    float aown = ho ? adv.y : adv.x;
    float s=0.f;
    for(int ph=0; ph<4; ++ph){
      int beg = (deg*ph)>>2;
      int end = (deg*(ph+1))>>2;
      for(int j=beg; j<end; j+=2){
        int c0 = cp[j];
        bool v1 = (j+1)<end;
        int c1 = cp[v1 ? j+1 : j];
        float sa = asrcf[c0*2+ho];
        float sb = asrcf[c1*2+ho];
        uint4 h0 = *(const uint4*)(hcg + (size_t)c0*OUTC);
        uint4 h1 = *(const uint4*)(hcg + (size_t)c1*OUTC);
        float e0 = sa+aown; e0 = fmaxf(e0, NEG_SLOPE*e0); e0 = fminf(e0,60.f);
        float e1 = sb+aown; e1 = fmaxf(e1, NEG_SLOPE*e1); e1 = fminf(e1,60.f);
        float p0 = __expf(e0), p1 = __expf(e1);
        if(!v1) p1 = 0.f;
        s += p0 + p1;
        acc[0] += p0*blo(h0.x) + p1*blo(h1.x);
        acc[1] += p0*bhi(h0.x) + p1*bhi(h1.x);
        acc[2] += p0*blo(h0.y) + p1*blo(h1.y);
        acc[3] += p0*bhi(h0.y) + p1*bhi(h1.y);
        acc[4] += p0*blo(h0.z) + p1*blo(h1.z);
        acc[5] += p0*bhi(h0.z) + p1*bhi(h1.z);
        acc[6] += p0*blo(h0.w) + p1*blo(h1.w);
        acc[7] += p0*bhi(h0.w) + p1*bhi(h1.w);
      }
      __syncthreads();   // phase barrier: keep block inside one src window
    }
    float inv = s>0.f ? 1.f/s : 0.f;
    if(ok){
      u16 o8[8];
      #pragma unroll
      for(int k=0;k<8;k++) o8[k]=f2b(acc[k]*inv + ldf(bias,cg*8+k,f));
      uint4 ov;
      ov.x=(u32)o8[0]|((u32)o8[1]<<16); ov.y=(u32)o8[2]|((u32)o8[3]<<16);
      ov.z=(u32)o8[4]|((u32)o8[5]<<16); ov.w=(u32)o8[6]|((u32)o8[7]<<16);
      *(uint4*)(houtb + (size_t)d*64 + cg*8) = ov;
    }
  } else {
    // ---- final layer: dual exp (cross-head accx), head mean via vbuf ----
    const float2* asrc2 = (const float2*)asrcf;
    const u16* hxg = hin + 64 + cg*2;
    float accx0=0.f, accx1=0.f;
    float s0=0.f, s1=0.f;
    for(int ph=0; ph<4; ++ph){
      int beg = (deg*ph)>>2;
      int end = (deg*(ph+1))>>2;
      for(int j=beg; j<end; j+=2){
        int c0 = cp[j];
        bool v1 = (j+1)<end;
        int c1 = cp[v1 ? j+1 : j];
        float2 sa = asrc2[c0];
        float2 sv = asrc2[c1];
        const u16* hp0 = hcg + (size_t)c0*OUTC;
        const u16* hp1 = hcg + (size_t)c1*OUTC;
        uint4 h0 = *(const uint4*)hp0;
        uint4 h1 = *(const uint4*)hp1;
        float e0 = sa.x+adv.x; e0 = fmaxf(e0, NEG_SLOPE*e0); e0 = fminf(e0,60.f);
        float e1 = sa.y+adv.y; e1 = fmaxf(e1, NEG_SLOPE*e1); e1 = fminf(e1,60.f);
        float p0 = __expf(e0), p1 = __expf(e1);
        float q0 = sv.x+adv.x; q0 = fmaxf(q0, NEG_SLOPE*q0); q0 = fminf(q0,60.f);
        float q1 = sv.y+adv.y; q1 = fmaxf(q1, NEG_SLOPE*q1); q1 = fminf(q1,60.f);
        float r0 = __expf(q0), r1 = __expf(q1);
        if(!v1){ r0=0.f; r1=0.f; }
        s0 += p0 + r0; s1 += p1 + r1;
        float pa = (cg<5)? p0 : p1;
        float pb = (cg<5)? r0 : r1;
        acc[0] += pa*blo(h0.x) + pb*blo(h1.x);
        acc[1] += pa*bhi(h0.x) + pb*bhi(h1.x);
        acc[2] += pa*blo(h0.y) + pb*blo(h1.y);
        acc[3] += pa*bhi(h0.y) + pb*bhi(h1.y);
        acc[4] += pa*blo(h0.z) + pb*blo(h1.z);
        acc[5] += pa*bhi(h0.z) + pb*bhi(h1.z);
        acc[6] += pa*blo(h0.w) + pb*blo(h1.w);
        acc[7] += pa*bhi(h0.w) + pb*bhi(h1.w);
        ushort2 ha = *(const ushort2*)(hxg + (size_t)c0*OUTC);
        ushort2 hb = *(const ushort2*)(hxg + (size_t)c1*OUTC);
        accx0 += p1*b2f(ha.x) + r1*b2f(hb.x);
        accx1 += p1*b2f(ha.y) + r1*b2f(hb.y);
      }
      __syncthreads();   // phase barrier
    }
    float inv0 = s0>0.f?1.f/s0:0.f, inv1 = s1>0.f?1.f/s1:0.f;
    if(ok){
      #pragma unroll
      for(int k=0;k<8;k++)
        vbuf[g][cg*8+k] = acc[k]*((cg<5)?inv0:inv1);
      vbuf[g][64+cg*2]   = accx0*inv1;
      vbuf[g][64+cg*2+1] = accx1*inv1;
    }
    __syncthreads();
    for(int idx=t; idx<32*40; idx+=256){
      int gg=idx/40, ch=idx-gg*40;
      if(gg<lim){
        int dd = rr*RSIZE + jb*32 + gg;
        float res = 0.5f*(vbuf[gg][ch] + vbuf[gg][40+ch]) + ldf(bias,ch,f);
        if(f) ((float*)outv)[(size_t)dd*40+ch] = res;
        else  ((__hip_bfloat16*)outv)[(size_t)dd*40+ch] = __float2bfloat16(res);
      }
    }
  }
}

// ---------------- batch norm (stats + coefficient finalize) ---------------
__global__ __launch_bounds__(256) void k_bnstats(const u16* __restrict__ h, float* __restrict__ stats){
  __shared__ float red[4][128];
  int t=threadIdx.x; int c=t&63; int g=t>>6;
  float s=0.f,q=0.f;
  for(int r=blockIdx.x*4+g; r<NNODES; r+=gridDim.x*4){
    float v=b2f(h[(size_t)r*64+c]); s+=v; q+=v*v;
  }
  red[g][c]=s; red[g][64+c]=q;
  __syncthreads();
  if(t<128){
    float tot=red[0][t]+red[1][t]+red[2][t]+red[3][t];
    atomicAdd(&stats[t], tot);
  }
}

__global__ void k_bnfinal(const float* __restrict__ stats,
                          const void* __restrict__ gm, const void* __restrict__ bt,
                          float2* __restrict__ bnab, const int* __restrict__ flagp){
  const int f = flagp[0];
  int c=threadIdx.x;
  if(c>=64) return;
  float mu=stats[c]*(1.0f/NNODES);
  float var=stats[64+c]*(1.0f/NNODES)-mu*mu;
  var = var>0.f?var:0.f;
  float A = ldf(gm,c,f)*rsqrtf(var+BN_EPS);
  float B = ldf(bt,c,f) - A*mu;
  bnab[c]=make_float2(A,B);
}

extern "C" void kernel_launch(void* const* d_in, const int* in_sizes, int n_in,
                              void* d_out, int out_size, void* d_ws, size_t ws_size,
                              hipStream_t stream){
  const void* x  =d_in[0];
  const int* ei =(const int*)d_in[1];
  const void* W0 =d_in[2];  const void* as0=d_in[3];  const void* ad0=d_in[4];
  const void* b0 =d_in[5];  const void* g0 =d_in[6];  const void* bt0=d_in[7];
  const void* W1 =d_in[8];  const void* as1=d_in[9];  const void* ad1=d_in[10];
  const void* b1 =d_in[11]; const void* g1 =d_in[12]; const void* bt1=d_in[13];
  const void* W2 =d_in[14]; const void* as2=d_in[15]; const void* ad2=d_in[16];
  const void* b2 =d_in[17];

  char* ws=(char*)d_ws;
  size_t off=0;
  auto alloc=[&](size_t bytes)->void*{ void* p=ws+off; off+=(bytes+255)&~(size_t)255; return p; };
  int*    flag   =(int*)   alloc(256);
  int*    row_ptr=(int*)   alloc((size_t)(NNODES+1)*4);
  int*    cnt    =(int*)   alloc((size_t)NNODES*4);
  int*    colx   =(int*)   alloc((size_t)ENTOT*4);
  int*    colx2  =(int*)   alloc((size_t)ENTOT*4);
  int*    bsum   =(int*)   alloc((size_t)SCAN_NB*4);
  int*    gptr   =(int*)   alloc(256);
  u32*    bkt    =(u32*)   alloc((size_t)NRANGE*BCAP*4);
  u16*    hA     =(u16*)   alloc((size_t)100032*80*2);   // aliased as lhist during CSR build
  u16*    hB0    =(u16*)   alloc((size_t)100032*64*2);
  u16*    hB1    =(u16*)   alloc((size_t)100032*64*2);
  float*  asrc   =(float*) alloc((size_t)NNODES*2*4);
  float*  adst   =(float*) alloc((size_t)NNODES*2*4);
  float*  stats  =(float*) alloc(128*4);
  float2* bnab   =(float2*)alloc(64*8);
  int*    lhist  =(int*)hA;   // 12.8 MB needed, hA is 16 MB; dead before gemm L0

  k_detect<<<1,256,0,stream>>>((const u16*)x, flag);

  // CSR: partition -> LDS hist -> chunk scan -> row_ptr scan -> LDS scatter
  (void)hipMemsetAsync(gptr,0,256,stream);
  k_part2  <<<PBLK,256,0,stream>>>(ei,gptr,bkt);
  k_hist4  <<<NRANGE*NB2,256,0,stream>>>(bkt,gptr,lhist);
  k_sumscan<<<(NNODES+255)/256,256,0,stream>>>(lhist,cnt);
  k_scan_a <<<SCAN_NB,256,0,stream>>>(cnt,bsum);
  k_scan_b <<<1,64,0,stream>>>(bsum);
  k_scan_c <<<SCAN_NB,256,0,stream>>>(cnt,bsum,row_ptr);
  k_scatter4<<<NRANGE*NB2,256,0,stream>>>(bkt,gptr,row_ptr,lhist,colx);
  k_binsort<<<(NNODES+255)/256,256,0,stream>>>(row_ptr,colx,colx2);

  int gG = (NNODES+63)/64;                 // 1563
  int gA = NRANGE * ((RSIZE + 31)/32);     // 8 x 391 = 3128 (32 dsts/block)
  // ---- layer 0 ----
  k_gemm_mfma<128,64,32,true ,false><<<gG,256,0,stream>>>(
      x,W0,as0,ad0,nullptr,hA,asrc,adst,flag);
  k_aggf<64,false><<<gA,256,0,stream>>>(row_ptr,colx2,hA,
      asrc,(const float2*)adst,b0,hB0,nullptr,flag);
  (void)hipMemsetAsync(stats,0,512,stream);
  k_bnstats<<<256,256,0,stream>>>(hB0,stats);
  k_bnfinal<<<1,64,0,stream>>>(stats,g0,bt0,bnab,flag);
  // ---- layer 1 ----
  k_gemm_mfma<64,64,32,false,true ><<<gG,256,0,stream>>>(
      hB0,W1,as1,ad1,bnab,hA,asrc,adst,flag);
  k_aggf<64,false><<<gA,256,0,stream>>>(row_ptr,colx2,hA,
      asrc,(const float2*)adst,b1,hB1,nullptr,flag);
  (void)hipMemsetAsync(stats,0,512,stream);
  k_bnstats<<<256,256,0,stream>>>(hB1,stats);
  k_bnfinal<<<1,64,0,stream>>>(stats,g1,bt1,bnab,flag);
  // ---- layer 2 (head mean -> d_out) ----
  k_gemm_mfma<64,80,40,false,true ><<<gG,256,0,stream>>>(
      hB1,W2,as2,ad2,bnab,hA,asrc,adst,flag);
  k_aggf<80,true ><<<gA,256,0,stream>>>(row_ptr,colx2,hA,
      asrc,(const float2*)adst,b2,nullptr,d_out,flag);

  (void)in_sizes;(void)n_in;(void)out_size;(void)ws_size;
}

// Round 9
// 447.068 us; speedup vs baseline: 1.5283x; 1.0335x over previous
//
#include <hip/hip_runtime.h>
#include <hip/hip_bf16.h>
#include <math.h>

// GAT: N=100000 nodes, E=1600000 edges (+N self loops), 3 layers.
// Inputs bf16 (runtime-detected flag kept). Intermediates bf16.
// CSR build: atomic-free counting sort (8 dst-range buckets), round-2 form
// (no binsort: ablation r6-r8 showed the sort+phase bundle costs ~29us net
// against ~15us of traffic savings). Aggregation: 8 dsts per wave
// (8 lanes/dst, 8ch/lane), shallow 2-edge loop; non-final layers use
// SINGLE-EXP per lane (own head only, own-sum normalize) -> ~25% less VALU
// per edge than dual-exp. XCD-swizzled blocks.

#define NNODES 100000
#define NEDGES 1600000
#define ENTOT  (NEDGES + NNODES)
#define NEG_SLOPE 0.2f
#define BN_EPS 1e-5f

#define NRANGE 8
#define RSIZE  (NNODES/NRANGE)     // 12500
#define BCAP   262144              // per-bucket capacity (mean 212.5k)
#define PBLK   2048                // partition blocks
#define NB2    32                  // chunks per range

typedef unsigned short u16;
typedef unsigned int u32;
typedef unsigned long long u64;
typedef __attribute__((ext_vector_type(8))) short short8;
typedef __attribute__((ext_vector_type(4))) float f32x4;

__device__ __forceinline__ float b2f(u16 u){ union{u32 i; float f;} v; v.i=((u32)u)<<16; return v.f; }
__device__ __forceinline__ float blo(u32 u){ union{u32 i; float f;} v; v.i=u<<16; return v.f; }
__device__ __forceinline__ float bhi(u32 u){ union{u32 i; float f;} v; v.i=u&0xffff0000u; return v.f; }
__device__ __forceinline__ u16 f2b(float x){ __hip_bfloat16 b=__float2bfloat16(x); return *(u16*)&b; }
__device__ __forceinline__ float ldf(const void* p, int i, int f){
  return f ? ((const float*)p)[i] : b2f(((const u16*)p)[i]);
}

// ---------------- dtype probe ----------------
__global__ void k_detect(const u16* __restrict__ x, int* __restrict__ flag){
  __shared__ int bad;
  if(threadIdx.x==0) bad=0;
  __syncthreads();
  int cnt=0;
  for(int i=threadIdx.x;i<4096;i+=256){
    u16 v = x[2*i];
    int ex = (v>>7)&0xff;
    if(ex==0xff || (ex==0 && (v&0x7fff)!=0)) cnt++;
  }
  atomicAdd(&bad,cnt);
  __syncthreads();
  if(threadIdx.x==0) flag[0] = (bad>4)?1:0;   // 1 = fp32, 0 = bf16
}

// ---------------- pass A: partition edges into 8 dst-range buckets ---------
__global__ __launch_bounds__(256) void k_part2(
    const int* __restrict__ ei, int* __restrict__ gptr, u32* __restrict__ bkt){
  __shared__ int lcnt[NRANGE], gbase[NRANGE];
  int t=threadIdx.x;
  if(t<NRANGE) lcnt[t]=0;
  __syncthreads();
  const int CH=(ENTOT+PBLK-1)/PBLK;   // 831
  int beg=blockIdx.x*CH, end=beg+CH; if(end>ENTOT) end=ENTOT;
  int nd[4], ns[4], nr[4], ne=0;
  for(int i=beg+t; i<end; i+=256){
    int d=(i<NEDGES)? ei[NEDGES+i] : (i-NEDGES);
    int s=(i<NEDGES)? ei[i] : d;
    nd[ne]=d; ns[ne]=s; ne++;
  }
  #pragma unroll 4
  for(int k=0;k<ne;k++) nr[k]=atomicAdd(&lcnt[nd[k]/RSIZE],1);
  __syncthreads();
  if(t<NRANGE) gbase[t]=atomicAdd(&gptr[t],lcnt[t]);
  __syncthreads();
  #pragma unroll 4
  for(int k=0;k<ne;k++){
    int r=nd[k]/RSIZE;
    u32 e = ((u32)(nd[k]-r*RSIZE)<<17) | (u32)ns[k];   // dst_local(14b)|src(17b)
    __builtin_nontemporal_store(e, &bkt[(size_t)r*BCAP + gbase[r] + nr[k]]);
  }
}

// ---------------- pass B0: per-(range,chunk) LDS histogram -----------------
__global__ __launch_bounds__(256) void k_hist4(
    const u32* __restrict__ bkt, const int* __restrict__ gptr, int* __restrict__ lhist){
  __shared__ int lh[RSIZE];
  int t=threadIdx.x;
  for(int i=t;i<RSIZE;i+=256) lh[i]=0;
  __syncthreads();
  int r = blockIdx.x & (NRANGE-1);
  int c = blockIdx.x >> 3;
  int n = gptr[r];
  int per=(n+NB2-1)/NB2;
  int beg=c*per, end=beg+per; if(end>n) end=n;
  const u32* bp = bkt + (size_t)r*BCAP;
  for(int i=beg+t;i<end;i+=256) atomicAdd(&lh[bp[i]>>17],1);
  __syncthreads();
  int* out = lhist + (size_t)(r*NB2+c)*RSIZE;
  for(int i=t;i<RSIZE;i+=256) out[i]=lh[i];
}

// ---------------- node-wise chunk-scan: cnt + in-place exclusive scan ------
__global__ __launch_bounds__(256) void k_sumscan(int* __restrict__ lhist, int* __restrict__ cnt){
  int n = blockIdx.x*256 + threadIdx.x;
  if(n>=NNODES) return;
  int r = n/RSIZE, i = n - r*RSIZE;
  int* base = lhist + (size_t)r*NB2*RSIZE + i;
  int run=0;
  #pragma unroll 8
  for(int c=0;c<NB2;c++){
    int v = base[(size_t)c*RSIZE];
    base[(size_t)c*RSIZE] = run;
    run += v;
  }
  cnt[n]=run;
}

// ---------------- prefix scan (row_ptr) ----------------
#define SCAN_M (NNODES+1)
#define SCAN_NB ((SCAN_M + 2047)/2048)

__global__ void k_scan_a(const int* __restrict__ cnt, int* __restrict__ bsum){
  __shared__ int red[256];
  int b=blockIdx.x, t=threadIdx.x;
  int base = b*2048 + t*8;
  int s=0;
  #pragma unroll
  for(int j=0;j<8;j++){ int idx=base+j; s += (idx<NNODES)? cnt[idx]:0; }
  red[t]=s; __syncthreads();
  for(int o=128;o>0;o>>=1){ if(t<o) red[t]+=red[t+o]; __syncthreads(); }
  if(t==0) bsum[b]=red[0];
}

__global__ void k_scan_b(int* bsum){
  if(threadIdx.x==0){
    int run=0;
    for(int i=0;i<SCAN_NB;i++){ int v=bsum[i]; bsum[i]=run; run+=v; }
  }
}

__global__ void k_scan_c(const int* __restrict__ cnt, const int* __restrict__ bsum,
                         int* __restrict__ row_ptr){
  __shared__ int lds[256];
  int b=blockIdx.x, t=threadIdx.x;
  int base=b*2048+t*8;
  int v[8]; int s=0;
  #pragma unroll
  for(int j=0;j<8;j++){ int idx=base+j; int x=(idx<NNODES)?cnt[idx]:0; v[j]=s; s+=x; }
  lds[t]=s; __syncthreads();
  for(int o=1;o<256;o<<=1){
    int other=0; if(t>=o) other=lds[t-o];
    __syncthreads();
    lds[t]+=other;
    __syncthreads();
  }
  int texcl = lds[t] - s;
  int off0 = bsum[b] + texcl;
  #pragma unroll
  for(int j=0;j<8;j++){ int idx=base+j; if(idx<SCAN_M) row_ptr[idx]=off0+v[j]; }
}

// ---------------- pass B1: LDS-offset scatter (no global atomics) ----------
__global__ __launch_bounds__(256) void k_scatter4(
    const u32* __restrict__ bkt, const int* __restrict__ gptr,
    const int* __restrict__ row_ptr, const int* __restrict__ lhist,
    int* __restrict__ col){
  __shared__ int lofs[RSIZE];
  int t=threadIdx.x;
  int r = blockIdx.x & (NRANGE-1);
  int c = blockIdx.x >> 3;
  int lo = r*RSIZE;
  const int* cb = lhist + (size_t)(r*NB2+c)*RSIZE;
  for(int i=t;i<RSIZE;i+=256) lofs[i] = row_ptr[lo+i] + cb[i];
  __syncthreads();
  int n = gptr[r];
  int per=(n+NB2-1)/NB2;
  int beg=c*per, end=beg+per; if(end>n) end=n;
  const u32* bp = bkt + (size_t)r*BCAP;
  for(int i=beg+t;i<end;i+=256){
    u32 e=bp[i];
    int pos=atomicAdd(&lofs[e>>17],1);
    col[pos]=(int)(e & 0x1FFFF);
  }
}

// ---------------- MFMA GEMM + fused BN/ELU + alpha epilogue ----------------
template<int K, int OUTC, int HID, bool XEXT, bool BN>
__global__ __launch_bounds__(256) void k_gemm_mfma(
    const void* __restrict__ xin, const void* __restrict__ W,
    const void* __restrict__ avs, const void* __restrict__ avd,
    const float2* __restrict__ bnab,
    u16* __restrict__ hout, float* __restrict__ asrc, float* __restrict__ adst,
    const int* __restrict__ flagp)
{
  const int f = flagp[0];
  constexpr int KP = K+8;          // WT row stride (u16), 16B-aligned rows
  constexpr int RS = OUTC+8;       // HROW row stride (u16)
  constexpr int NT = OUTC/16;      // col tiles per wave
  constexpr int KQ = K/32;         // mfma K steps
  __shared__ __align__(16) u16 WT[OUTC*KP];
  __shared__ __align__(16) u16 HROW[4*16*RS];
  __shared__ float AVb[2*OUTC];
  __shared__ float2 BB[K];
  int t=threadIdx.x;
  const u16* Wu=(const u16*)W; const float* Wf=(const float*)W;
  for(int i8=t*8; i8<K*OUTC; i8+=256*8){
    int k=i8/OUTC, c0=i8-k*OUTC;     // OUTC divisible by 8 -> row-local
    u16 w8[8];
    if(f){
      const float* wp=Wf+i8;
      float4 a=*(const float4*)wp, b=*(const float4*)(wp+4);
      w8[0]=f2b(a.x);w8[1]=f2b(a.y);w8[2]=f2b(a.z);w8[3]=f2b(a.w);
      w8[4]=f2b(b.x);w8[5]=f2b(b.y);w8[6]=f2b(b.z);w8[7]=f2b(b.w);
    } else {
      uint4 q=*(const uint4*)(Wu+i8);
      w8[0]=q.x&0xffff;w8[1]=q.x>>16;w8[2]=q.y&0xffff;w8[3]=q.y>>16;
      w8[4]=q.z&0xffff;w8[5]=q.z>>16;w8[6]=q.w&0xffff;w8[7]=q.w>>16;
    }
    #pragma unroll
    for(int u=0;u<8;u++) WT[(c0+u)*KP + k] = w8[u];
  }
  for(int idx=t; idx<2*OUTC; idx+=256)
    AVb[idx] = (idx<OUTC)? ldf(avs,idx,f) : ldf(avd,idx-OUTC,f);
  if(BN) for(int idx=t; idx<K; idx+=256) BB[idx]=bnab[idx];
  __syncthreads();

  int wv=t>>6, lane=t&63;
  int m=lane&15, quad=lane>>4;
  int grow0 = blockIdx.x*64 + wv*16;
  int growA = grow0 + m;
  bool avalid = growA < NNODES;
  int growC = avalid ? growA : 0;

  f32x4 acc[NT] = {};
  #pragma unroll
  for(int kq=0;kq<KQ;kq++){
    int k0 = kq*32 + quad*8;
    union{ u32 u[4]; short8 s8; } A;
    if(XEXT && f==1){
      const float* xr=(const float*)xin + (size_t)growC*K + k0;
      float4 p=*(const float4*)xr, q=*(const float4*)(xr+4);
      A.u[0]=f2b(p.x)|((u32)f2b(p.y)<<16);
      A.u[1]=f2b(p.z)|((u32)f2b(p.w)<<16);
      A.u[2]=f2b(q.x)|((u32)f2b(q.y)<<16);
      A.u[3]=f2b(q.z)|((u32)f2b(q.w)<<16);
    } else {
      uint4 q=*(const uint4*)((const u16*)xin + (size_t)growC*K + k0);
      A.u[0]=q.x; A.u[1]=q.y; A.u[2]=q.z; A.u[3]=q.w;
    }
    if(BN){
      #pragma unroll
      for(int j=0;j<4;j++){
        float lo=b2f(A.u[j]&0xffff), hi=b2f(A.u[j]>>16);
        float2 c1=BB[k0+2*j], c2=BB[k0+2*j+1];
        lo=c1.x*lo+c1.y; lo = lo>0.f? lo : __expf(lo)-1.f;
        hi=c2.x*hi+c2.y; hi = hi>0.f? hi : __expf(hi)-1.f;
        A.u[j]=f2b(lo)|((u32)f2b(hi)<<16);
      }
    }
    #pragma unroll
    for(int nt=0;nt<NT;nt++){
      union{ uint4 q; short8 s8; } Bf;
      Bf.q = *(const uint4*)&WT[(nt*16+m)*KP + k0];
      acc[nt] = __builtin_amdgcn_mfma_f32_16x16x32_bf16(A.s8, Bf.s8, acc[nt], 0,0,0);
    }
  }
  u16* hr = &HROW[wv*16*RS];
  #pragma unroll
  for(int nt=0;nt<NT;nt++){
    #pragma unroll
    for(int reg=0;reg<4;reg++)
      hr[(quad*4+reg)*RS + nt*16+m] = f2b(acc[nt][reg]);
  }
  __syncthreads();
  {
    int row=lane&15, task=quad, head=task&1, sd=task>>1;
    float p=0.f;
    const u16* hrow=&hr[row*RS + head*HID];
    const float* av=&AVb[sd*OUTC + head*HID];
    #pragma unroll 8
    for(int c=0;c<HID;c++) p += b2f(hrow[c])*av[c];
    int grow=grow0+row;
    if(grow<NNODES){ (sd? adst:asrc)[grow*2+head]=p; }
  }
  {
    constexpr int CH8 = OUTC/8;
    for(int idx=lane; idx<16*CH8; idx+=64){
      int rr=idx/CH8, c8=idx-rr*CH8;
      int grow=grow0+rr;
      if(grow<NNODES)
        *(uint4*)(hout + (size_t)grow*OUTC + c8*8) = *(const uint4*)&hr[rr*RS + c8*8];
    }
  }
}

// ---------------- fused softmax + gather-aggregate -------------------------
// 8 dsts per wave: group g = tid>>3 (32 dsts/block), lane cg = tid&7 owns
// channels [cg*8, cg*8+8). Shallow 2-edge loop (pipeline depth is
// time-neutral per r1/r2 A/B). Non-final: SINGLE exp per lane (own head
// only, own-sum normalize). FINAL: dual exp (cross-head accx) + head mean
// via vbuf. XCD-swizzled (range = blockIdx%8).
template<int OUTC, bool FINAL>
__global__ __launch_bounds__(256) void k_aggf(
  const int* __restrict__ row_ptr, const int* __restrict__ col,
  const u16* __restrict__ hin, const float* __restrict__ asrcf,
  const float2* __restrict__ adst2, const void* __restrict__ bias,
  u16* __restrict__ houtb, void* __restrict__ outv, const int* __restrict__ flagp)
{
  const int f = flagp[0];
  __shared__ float vbuf[FINAL?32:1][84];
  int t = threadIdx.x;
  int g  = t>>3;            // dst group within block, 0..31
  int cg = t&7;             // channel group
  int rr = blockIdx.x & 7, jb = blockIdx.x >> 3;
  int lim = RSIZE - jb*32;              // valid groups in this block
  bool ok = g < lim;
  int d = rr*RSIZE + jb*32 + g;
  int base=0, deg=0;
  float2 adv = make_float2(0.f,0.f);
  if(ok){
    base = row_ptr[d];
    deg  = row_ptr[d+1] - base;
    adv  = adst2[d];
  }
  const int* cp  = col + base;
  const u16* hcg = hin + cg*8;          // per-lane channel base
  float acc[8]={0,0,0,0,0,0,0,0};

  if(!FINAL){
    // ---- single-exp path: lane only needs its own head ----
    int ho = (cg>=4)?1:0;
    float aown = ho ? adv.y : adv.x;
    float s=0.f;
    for(int j=0;j<deg;j+=2){
      int c0 = cp[j];
      bool v1 = (j+1)<deg;
      int c1 = cp[v1 ? j+1 : j];
      float sa = asrcf[c0*2+ho];
      float sb = asrcf[c1*2+ho];
      uint4 h0 = *(const uint4*)(hcg + (size_t)c0*OUTC);
      uint4 h1 = *(const uint4*)(hcg + (size_t)c1*OUTC);
      float e0 = sa+aown; e0 = fmaxf(e0, NEG_SLOPE*e0); e0 = fminf(e0,60.f);
      float e1 = sb+aown; e1 = fmaxf(e1, NEG_SLOPE*e1); e1 = fminf(e1,60.f);
      float p0 = __expf(e0), p1 = __expf(e1);
      if(!v1) p1 = 0.f;
      s += p0 + p1;
      acc[0] += p0*blo(h0.x) + p1*blo(h1.x);
      acc[1] += p0*bhi(h0.x) + p1*bhi(h1.x);
      acc[2] += p0*blo(h0.y) + p1*blo(h1.y);
      acc[3] += p0*bhi(h0.y) + p1*bhi(h1.y);
      acc[4] += p0*blo(h0.z) + p1*blo(h1.z);
      acc[5] += p0*bhi(h0.z) + p1*bhi(h1.z);
      acc[6] += p0*blo(h0.w) + p1*blo(h1.w);
      acc[7] += p0*bhi(h0.w) + p1*bhi(h1.w);
    }
    float inv = s>0.f ? 1.f/s : 0.f;
    if(ok){
      u16 o8[8];
      #pragma unroll
      for(int k=0;k<8;k++) o8[k]=f2b(acc[k]*inv + ldf(bias,cg*8+k,f));
      uint4 ov;
      ov.x=(u32)o8[0]|((u32)o8[1]<<16); ov.y=(u32)o8[2]|((u32)o8[3]<<16);
      ov.z=(u32)o8[4]|((u32)o8[5]<<16); ov.w=(u32)o8[6]|((u32)o8[7]<<16);
      *(uint4*)(houtb + (size_t)d*64 + cg*8) = ov;
    }
  } else {
    // ---- final layer: dual exp (cross-head accx), head mean via vbuf ----
    const float2* asrc2 = (const float2*)asrcf;
    const u16* hxg = hin + 64 + cg*2;
    float accx0=0.f, accx1=0.f;
    float s0=0.f, s1=0.f;
    for(int j=0;j<deg;j+=2){
      int c0 = cp[j];
      bool v1 = (j+1)<deg;
      int c1 = cp[v1 ? j+1 : j];
      float2 sa = asrc2[c0];
      float2 sv = asrc2[c1];
      const u16* hp0 = hcg + (size_t)c0*OUTC;
      const u16* hp1 = hcg + (size_t)c1*OUTC;
      uint4 h0 = *(const uint4*)hp0;
      uint4 h1 = *(const uint4*)hp1;
      float e0 = sa.x+adv.x; e0 = fmaxf(e0, NEG_SLOPE*e0); e0 = fminf(e0,60.f);
      float e1 = sa.y+adv.y; e1 = fmaxf(e1, NEG_SLOPE*e1); e1 = fminf(e1,60.f);
      float p0 = __expf(e0), p1 = __expf(e1);
      float q0 = sv.x+adv.x; q0 = fmaxf(q0, NEG_SLOPE*q0); q0 = fminf(q0,60.f);
      float q1 = sv.y+adv.y; q1 = fmaxf(q1, NEG_SLOPE*q1); q1 = fminf(q1,60.f);
      float r0 = __expf(q0), r1 = __expf(q1);
      if(!v1){ r0=0.f; r1=0.f; }
      s0 += p0 + r0; s1 += p1 + r1;
      float pa = (cg<5)? p0 : p1;
      float pb = (cg<5)? r0 : r1;
      acc[0] += pa*blo(h0.x) + pb*blo(h1.x);
      acc[1] += pa*bhi(h0.x) + pb*bhi(h1.x);
      acc[2] += pa*blo(h0.y) + pb*blo(h1.y);
      acc[3] += pa*bhi(h0.y) + pb*bhi(h1.y);
      acc[4] += pa*blo(h0.z) + pb*blo(h1.z);
      acc[5] += pa*bhi(h0.z) + pb*bhi(h1.z);
      acc[6] += pa*blo(h0.w) + pb*blo(h1.w);
      acc[7] += pa*bhi(h0.w) + pb*bhi(h1.w);
      ushort2 ha = *(const ushort2*)(hxg + (size_t)c0*OUTC);
      ushort2 hb = *(const ushort2*)(hxg + (size_t)c1*OUTC);
      accx0 += p1*b2f(ha.x) + r1*b2f(hb.x);
      accx1 += p1*b2f(ha.y) + r1*b2f(hb.y);
    }
    float inv0 = s0>0.f?1.f/s0:0.f, inv1 = s1>0.f?1.f/s1:0.f;
    if(ok){
      #pragma unroll
      for(int k=0;k<8;k++)
        vbuf[g][cg*8+k] = acc[k]*((cg<5)?inv0:inv1);
      vbuf[g][64+cg*2]   = accx0*inv1;
      vbuf[g][64+cg*2+1] = accx1*inv1;
    }
    __syncthreads();
    for(int idx=t; idx<32*40; idx+=256){
      int gg=idx/40, ch=idx-gg*40;
      if(gg<lim){
        int dd = rr*RSIZE + jb*32 + gg;
        float res = 0.5f*(vbuf[gg][ch] + vbuf[gg][40+ch]) + ldf(bias,ch,f);
        if(f) ((float*)outv)[(size_t)dd*40+ch] = res;
        else  ((__hip_bfloat16*)outv)[(size_t)dd*40+ch] = __float2bfloat16(res);
      }
    }
  }
}

// ---------------- batch norm (stats + coefficient finalize) ---------------
__global__ __launch_bounds__(256) void k_bnstats(const u16* __restrict__ h, float* __restrict__ stats){
  __shared__ float red[4][128];
  int t=threadIdx.x; int c=t&63; int g=t>>6;
  float s=0.f,q=0.f;
  for(int r=blockIdx.x*4+g; r<NNODES; r+=gridDim.x*4){
    float v=b2f(h[(size_t)r*64+c]); s+=v; q+=v*v;
  }
  red[g][c]=s; red[g][64+c]=q;
  __syncthreads();
  if(t<128){
    float tot=red[0][t]+red[1][t]+red[2][t]+red[3][t];
    atomicAdd(&stats[t], tot);
  }
}

__global__ void k_bnfinal(const float* __restrict__ stats,
                          const void* __restrict__ gm, const void* __restrict__ bt,
                          float2* __restrict__ bnab, const int* __restrict__ flagp){
  const int f = flagp[0];
  int c=threadIdx.x;
  if(c>=64) return;
  float mu=stats[c]*(1.0f/NNODES);
  float var=stats[64+c]*(1.0f/NNODES)-mu*mu;
  var = var>0.f?var:0.f;
  float A = ldf(gm,c,f)*rsqrtf(var+BN_EPS);
  float B = ldf(bt,c,f) - A*mu;
  bnab[c]=make_float2(A,B);
}

extern "C" void kernel_launch(void* const* d_in, const int* in_sizes, int n_in,
                              void* d_out, int out_size, void* d_ws, size_t ws_size,
                              hipStream_t stream){
  const void* x  =d_in[0];
  const int* ei =(const int*)d_in[1];
  const void* W0 =d_in[2];  const void* as0=d_in[3];  const void* ad0=d_in[4];
  const void* b0 =d_in[5];  const void* g0 =d_in[6];  const void* bt0=d_in[7];
  const void* W1 =d_in[8];  const void* as1=d_in[9];  const void* ad1=d_in[10];
  const void* b1 =d_in[11]; const void* g1 =d_in[12]; const void* bt1=d_in[13];
  const void* W2 =d_in[14]; const void* as2=d_in[15]; const void* ad2=d_in[16];
  const void* b2 =d_in[17];

  char* ws=(char*)d_ws;
  size_t off=0;
  auto alloc=[&](size_t bytes)->void*{ void* p=ws+off; off+=(bytes+255)&~(size_t)255; return p; };
  int*    flag   =(int*)   alloc(256);
  int*    row_ptr=(int*)   alloc((size_t)(NNODES+1)*4);
  int*    cnt    =(int*)   alloc((size_t)NNODES*4);
  int*    colx   =(int*)   alloc((size_t)ENTOT*4);
  int*    bsum   =(int*)   alloc((size_t)SCAN_NB*4);
  int*    gptr   =(int*)   alloc(256);
  u32*    bkt    =(u32*)   alloc((size_t)NRANGE*BCAP*4);
  u16*    hA     =(u16*)   alloc((size_t)100032*80*2);   // aliased as lhist during CSR build
  u16*    hB0    =(u16*)   alloc((size_t)100032*64*2);
  u16*    hB1    =(u16*)   alloc((size_t)100032*64*2);
  float*  asrc   =(float*) alloc((size_t)NNODES*2*4);
  float*  adst   =(float*) alloc((size_t)NNODES*2*4);
  float*  stats  =(float*) alloc(128*4);
  float2* bnab   =(float2*)alloc(64*8);
  int*    lhist  =(int*)hA;   // 12.8 MB needed, hA is 16 MB; dead before gemm L0

  k_detect<<<1,256,0,stream>>>((const u16*)x, flag);

  // CSR: partition -> LDS hist -> chunk scan -> row_ptr scan -> LDS scatter
  (void)hipMemsetAsync(gptr,0,256,stream);
  k_part2  <<<PBLK,256,0,stream>>>(ei,gptr,bkt);
  k_hist4  <<<NRANGE*NB2,256,0,stream>>>(bkt,gptr,lhist);
  k_sumscan<<<(NNODES+255)/256,256,0,stream>>>(lhist,cnt);
  k_scan_a <<<SCAN_NB,256,0,stream>>>(cnt,bsum);
  k_scan_b <<<1,64,0,stream>>>(bsum);
  k_scan_c <<<SCAN_NB,256,0,stream>>>(cnt,bsum,row_ptr);
  k_scatter4<<<NRANGE*NB2,256,0,stream>>>(bkt,gptr,row_ptr,lhist,colx);

  int gG = (NNODES+63)/64;                 // 1563
  int gA = NRANGE * ((RSIZE + 31)/32);     // 8 x 391 = 3128 (32 dsts/block)
  // ---- layer 0 ----
  k_gemm_mfma<128,64,32,true ,false><<<gG,256,0,stream>>>(
      x,W0,as0,ad0,nullptr,hA,asrc,adst,flag);
  k_aggf<64,false><<<gA,256,0,stream>>>(row_ptr,colx,hA,
      asrc,(const float2*)adst,b0,hB0,nullptr,flag);
  (void)hipMemsetAsync(stats,0,512,stream);
  k_bnstats<<<256,256,0,stream>>>(hB0,stats);
  k_bnfinal<<<1,64,0,stream>>>(stats,g0,bt0,bnab,flag);
  // ---- layer 1 ----
  k_gemm_mfma<64,64,32,false,true ><<<gG,256,0,stream>>>(
      hB0,W1,as1,ad1,bnab,hA,asrc,adst,flag);
  k_aggf<64,false><<<gA,256,0,stream>>>(row_ptr,colx,hA,
      asrc,(const float2*)adst,b1,hB1,nullptr,flag);
  (void)hipMemsetAsync(stats,0,512,stream);
  k_bnstats<<<256,256,0,stream>>>(hB1,stats);
  k_bnfinal<<<1,64,0,stream>>>(stats,g1,bt1,bnab,flag);
  // ---- layer 2 (head mean -> d_out) ----
  k_gemm_mfma<64,80,40,false,true ><<<gG,256,0,stream>>>(
      hB1,W2,as2,ad2,bnab,hA,asrc,adst,flag);
  k_aggf<80,true ><<<gA,256,0,stream>>>(row_ptr,colx,hA,
      asrc,(const float2*)adst,b2,nullptr,d_out,flag);

  (void)in_sizes;(void)n_in;(void)out_size;(void)ws_size;
}